// Round 3
// baseline (435.642 us; speedup 1.0000x reference)
//
#include <hip/hip_runtime.h>
#include <math.h>

// FICONN forward, split-bf16 MFMA (hi+lo, 3-product) + segment-parallel unitary build.
// R9 vs R8: main kernel rebuilt as a TWO-BUFFER SKEWED PIPELINE (T15 pattern).
//   R8 counters: MfmaUtil 40 + VALUBusy 51 = 91% -> phases alternate pipe-serially
//   (wall = T_mfma + T_valu + drain). Fix: block's 64 samples split into two
//   32-sample F-buffers A/B, skewed half a stage: each barrier phase executes
//   {MFMA of X} + {epilogue of Y} back-to-back -> matrix pipe and VALU pipe fed
//   in the same window, same wave. Per-sample arithmetic bit-identical to R8.
//   LDS unchanged 32768 B (FA_h|FA_l|FB_h|FB_l x 8 KiB), barrier count unchanged.

#define NN 64
#define LL 5
#define NMZI 2016
#define C_HALF 0.7071067811865476f
#define GAMMA_ 0.05f
#define SENSRESP 0.0008f     // SENS*RESP

#define AH_SHORTS   114688   // 7 slots * 8Mt * 4Kt * 512 shorts
#define FLOAT_BYTE  458752   // nofuC (1024 f) + W3T (768 f)
#define PSEG_BYTE   466944   // 5l x 4s x 64c x 64r float2 = 655360 B

typedef short short8 __attribute__((ext_vector_type(8)));
typedef float f32x4  __attribute__((ext_vector_type(4)));

union U4S8 { uint4 u; short8 s; };

#define MFMA16(a, b, c) __builtin_amdgcn_mfma_f32_16x16x32_bf16((a), (b), (c), 0, 0, 0)

__device__ __forceinline__ unsigned short f2bf(float f) {
    unsigned u = __float_as_uint(f);
    unsigned r = u + 0x7fffu + ((u >> 16) & 1u);
    return (unsigned short)(r >> 16);
}
__device__ __forceinline__ float bf2f(unsigned short h) {
    return __uint_as_float(((unsigned)h) << 16);
}
// packed bf16 convert: bits[15:0]=bf16(a), bits[31:16]=bf16(b)  (RNE)
__device__ __forceinline__ unsigned cvtpk(float a, float b) {
    unsigned r;
    asm("v_cvt_pk_bf16_f32 %0, %1, %2" : "=v"(r) : "v"(a), "v"(b));
    return r;
}
// split 4 floats into packed-bf16 hi plane + packed-bf16 residual plane.
__device__ __forceinline__ void split4(const float* v, uint2& hi, uint2& lo) {
    hi.x = cvtpk(v[0], v[1]);
    hi.y = cvtpk(v[2], v[3]);
    float l0 = v[0] - __uint_as_float(hi.x << 16);
    float l1 = v[1] - __uint_as_float(hi.x & 0xffff0000u);
    float l2 = v[2] - __uint_as_float(hi.y << 16);
    float l3 = v[3] - __uint_as_float(hi.y & 0xffff0000u);
    lo.x = cvtpk(l0, l1);
    lo.y = cvtpk(l2, l3);
}
// frag-linear offset (in shorts) of element (m,k) of A-slot l
__device__ __forceinline__ int afrag_off(int l, int m, int k) {
    return ((((l * 8 + (m >> 4)) * 4 + (k >> 5)) << 9)
          + ((((k >> 3) & 3) * 16 + (m & 15)) << 3) + (k & 7));
}

// ---------------------------------------------------------------------------
// Kernel 1: build_seg. 20 blocks (layer l, segment s) x 64 threads.
// ---------------------------------------------------------------------------
template<int I0, int I1>
__device__ __forceinline__ void run_scan(const float cs[][4], float* ur, float* ui)
{
    int m = 0;
    #pragma unroll
    for (int i = I0; i < I1; ++i) {
        #pragma unroll
        for (int j = i + 1; j < NN; ++j) {
            float cph = cs[m][0], sph = cs[m][1];
            float cct = cs[m][2], cst = cs[m][3];
            float tr = cph * ur[j] - sph * ui[j];
            float ti = cph * ui[j] + sph * ur[j];
            float ar = ur[i] + tr, ai = ui[i] + ti;
            float sr = ur[i] - tr, si = ui[i] - ti;
            ur[i] = C_HALF * ar;
            ui[i] = C_HALF * ai;
            ur[j] = cct * sr - cst * si;
            ui[j] = cct * si + cst * sr;
            ++m;
        }
    }
}

__global__ __launch_bounds__(64) void build_seg(
    const float* __restrict__ mzi, float2* __restrict__ Pg)
{
    const int b = blockIdx.x;
    const int l = b >> 2, s = b & 3;
    const int c = threadIdx.x;

    __shared__ float cs[531][4];
    const int M0s[5] = {0, 531, 1026, 1488, 2016};
    const int m0 = M0s[s], cnt = M0s[s + 1] - m0;

    for (int t = c; t < cnt; t += 64) {
        int m = m0 + t;
        float th = mzi[l * 2 * NMZI + 2 * m];
        float ph = mzi[l * 2 * NMZI + 2 * m + 1];
        float sth, cth, sph, cph;
        sincosf(th, &sth, &cth);
        sincosf(ph, &sph, &cph);
        cs[t][0] = cph; cs[t][1] = sph;
        cs[t][2] = C_HALF * cth; cs[t][3] = C_HALF * sth;
    }
    __syncthreads();

    float ur[NN], ui[NN];
    #pragma unroll
    for (int r = 0; r < NN; ++r) { ur[r] = (r == c) ? 1.f : 0.f; ui[r] = 0.f; }

    switch (s) {
        case 0: run_scan<0,  9>(cs, ur, ui); break;
        case 1: run_scan<9, 19>(cs, ur, ui); break;
        case 2: run_scan<19,31>(cs, ur, ui); break;
        default:run_scan<31,63>(cs, ur, ui); break;
    }

    // store column-major: Pg[(l*4+s)*4096 + c*64 + r]
    float2* P = Pg + ((size_t)(l * 4 + s) << 12) + (c << 6);
    #pragma unroll
    for (int r = 0; r < NN; ++r) P[r] = make_float2(ur[r], ui[r]);
}

// ---------------------------------------------------------------------------
// Kernel 2: build_combine. 5 blocks x 256 threads.
// ---------------------------------------------------------------------------
__device__ __forceinline__ void cpass(const float2* A, const float2* Bm,
                                      int rq, int c, float2* y)
{
    #pragma unroll
    for (int r = 0; r < 16; ++r) y[r] = make_float2(0.f, 0.f);
    #pragma unroll 2
    for (int k = 0; k < 64; ++k) {
        float2 x = Bm[c * 65 + k];                  // own column, 2-way bank (free)
        #pragma unroll
        for (int r = 0; r < 16; ++r) {
            float2 a = A[k * 65 + 16 * rq + r];     // wave-uniform -> broadcast
            y[r].x = fmaf(a.x, x.x, fmaf(-a.y, x.y, y[r].x));
            y[r].y = fmaf(a.x, x.y, fmaf( a.y, x.x, y[r].y));
        }
    }
}

__device__ __forceinline__ void store_split(unsigned short* AH, unsigned short* AL,
                                            int l, int m, int k, float v)
{
    int o = afrag_off(l, m, k);
    unsigned short h = f2bf(v);
    AH[o] = h;
    AL[o] = f2bf(v - bf2f(h));
}

__global__ __launch_bounds__(256) void build_combine(
    const float2* __restrict__ Pg, const float* __restrict__ oph,
    unsigned short* __restrict__ AH)
{
    unsigned short* AL = AH + AH_SHORTS;
    extern __shared__ float cl[];
    float2* B0 = (float2*)cl;              // 64 x 65 f2 each
    float2* B1 = B0 + 4160;
    float2* B2 = B1 + 4160;
    float2* B3 = B2 + 4160;
    float2* ocs = B3 + 4160;               // 64 f2

    const int l = blockIdx.x;
    const int tid = threadIdx.x;
    const int rq = tid >> 6, c = tid & 63;

    const float2* Pgl = Pg + ((size_t)l << 14);
    #pragma unroll
    for (int sb = 0; sb < 4; ++sb) {
        float2* Bb = B0 + sb * 4160;
        #pragma unroll
        for (int i = 0; i < 16; ++i) {
            int idx = tid + i * 256;
            Bb[(idx >> 6) * 65 + (idx & 63)] = Pgl[(sb << 12) + idx];
        }
    }
    if (tid < NN) {
        float sp, cp; sincosf(oph[l * NN + tid], &sp, &cp);
        ocs[tid] = make_float2(cp, sp);
    }
    __syncthreads();

    float2 t1[16], t2[16];
    cpass(B1, B0, rq, c, t1);   // T1 = P1*P0
    cpass(B3, B2, rq, c, t2);   // T2 = P3*P2
    __syncthreads();
    #pragma unroll
    for (int r = 0; r < 16; ++r) {
        B0[c * 65 + 16 * rq + r] = t1[r];
        B2[c * 65 + 16 * rq + r] = t2[r];
    }
    __syncthreads();

    float2 u[16];
    cpass(B2, B0, rq, c, u);    // U = T2*T1

    #pragma unroll
    for (int r = 0; r < 16; ++r) {
        int mr = 16 * rq + r;
        float2 oc = ocs[mr];
        float vr = oc.x * u[r].x - oc.y * u[r].y;   // e^{i psi_mr} * U[mr][c]
        float vi = oc.x * u[r].y + oc.y * u[r].x;
        // Mat = [[Ur,-Ui],[Ui,Ur]]
        store_split(AH, AL, l, mr,      c,      vr);
        store_split(AH, AL, l, mr,      c + 64, -vi);
        store_split(AH, AL, l, mr + 64, c,      vi);
        store_split(AH, AL, l, mr + 64, c + 64, vr);
    }
}

// ---------------------------------------------------------------------------
// Kernel 3: W1 -> A-slot 5, W2 -> A-slot 6 (split bf16 frags), W3T, nofu consts.
// ---------------------------------------------------------------------------
__global__ void prep_weights(const float* __restrict__ W1,
                             const float* __restrict__ W2,
                             const float* __restrict__ W3,
                             const float* __restrict__ beta_param,
                             const float* __restrict__ det0,
                             unsigned short* __restrict__ AH)
{
    unsigned short* AL = AH + AH_SHORTS;
    float* fbase = (float*)((char*)AH + FLOAT_BYTE);
    float* nofuF = fbase;               // 1024 floats (256 x float4)
    float* W3T   = fbase + 1024;        // 768 floats

    int idx = blockIdx.x * 256 + threadIdx.x;
    if (idx < 8192) {                        // W1 (128x64)
        int mm = idx >> 6, k = idx & 63;
        float v = W1[idx];
        unsigned short h = f2bf(v);
        int o = afrag_off(5, mm, k);
        AH[o] = h; AL[o] = f2bf(v - bf2f(h));
    } else if (idx < 16384) {                // W2 (64x128)
        int t = idx - 8192;
        int mm = t >> 7, k = t & 127;
        float v = W2[t];
        unsigned short h = f2bf(v);
        int o = afrag_off(6, mm, k);
        AH[o] = h; AL[o] = f2bf(v - bf2f(h));
    } else if (idx < 17152) {                // W3 (12x64) -> W3T[j][r]
        int t = idx - 16384;
        int r = t >> 6, j = t & 63;
        W3T[j * 12 + r] = W3[t];
    } else if (idx < 17408) {                // nofu consts, t = l*64+row
        int t = idx - 17152;
        float bp = beta_param[t];
        float beta = 1.f / (1.f + expf(-bp));
        float* p = nofuF + t * 4;
        p[0] = SENSRESP * beta;
        p[1] = sqrtf(fmaxf(1.f - beta, 0.f)) * GAMMA_;
        p[2] = det0[t];
        p[3] = 0.f;
    }
}

// ---------------------------------------------------------------------------
// mm2: acc = A_slot x F_buf over 2 N-tiles (32 samples). PAIR: Mt0+4 -> acc1.
// Fb = byte base of buffer (hi plane at +0, lo plane at +8192).
// ---------------------------------------------------------------------------
template<int K4, bool PAIR>
__device__ __forceinline__ void mm2(
    const unsigned short* __restrict__ AH, const unsigned short* __restrict__ AL,
    const char* Fb, int slot, int mp, int lane, int q, int x0, const int* rowb,
    f32x4* acc0, f32x4* acc1)
{
    #pragma unroll
    for (int t = 0; t < 2; ++t)
        #pragma unroll
        for (int r = 0; r < 4; ++r) { acc0[t][r] = 0.f; if (PAIR) acc1[t][r] = 0.f; }

    #pragma unroll
    for (int Kt = 0; Kt < K4; ++Kt) {
        int off0 = (((slot * 8 + mp) * 4 + Kt) << 9);
        U4S8 ah0, al0, ah1, al1;
        ah0.u = ((const uint4*)(AH + off0))[lane];
        al0.u = ((const uint4*)(AL + off0))[lane];
        if (PAIR) {
            ah1.u = ((const uint4*)(AH + off0 + 8192))[lane];   // Mt0+4
            al1.u = ((const uint4*)(AL + off0 + 8192))[lane];
        }
        const int cb = (64 * Kt + 16 * q) ^ x0;
        #pragma unroll
        for (int t = 0; t < 2; ++t) {
            short8 bh = *(const short8*)(Fb + rowb[t] + cb);
            short8 bl = *(const short8*)(Fb + 8192 + rowb[t] + cb);
            acc0[t] = MFMA16(ah0.s, bh, acc0[t]);
            acc0[t] = MFMA16(ah0.s, bl, acc0[t]);
            acc0[t] = MFMA16(al0.s, bh, acc0[t]);
            if (PAIR) {
                acc1[t] = MFMA16(ah1.s, bh, acc1[t]);
                acc1[t] = MFMA16(ah1.s, bl, acc1[t]);
                acc1[t] = MFMA16(al1.s, bh, acc1[t]);
            }
        }
    }
}

// ---------------------------------------------------------------------------
// Epilogues (write split-bf16 back into buffer Fb).
// ---------------------------------------------------------------------------
__device__ __forceinline__ void epi_nofu(
    const float4* __restrict__ nofuC, int l, int kw, int cwr, const int* rowb,
    char* Fb, f32x4* acc0, f32x4* acc1)
{
    float4 nc[4];
    #pragma unroll
    for (int r = 0; r < 4; ++r) nc[r] = nofuC[l * 64 + kw + r];
    #pragma unroll
    for (int t = 0; t < 2; ++t) {
        float wr[4], wi[4];
        #pragma unroll
        for (int r = 0; r < 4; ++r) {
            float yr = acc0[t][r], yi = acc1[t][r];
            float4 c = nc[r];
            float p   = fmaf(yr, yr, yi * yi);
            float det = fmaf(c.x, p, c.z);
            float sc  = c.y * __builtin_amdgcn_rcpf(fmaf(det, det, GAMMA_ * GAMMA_));
            float tr = sc * GAMMA_, ti = sc * det;
            wr[r] = fmaf(tr, yr,  ti * yi);
            wi[r] = fmaf(tr, yi, -ti * yr);
        }
        uint2 hi, lo;
        split4(wr, hi, lo);
        *(uint2*)(Fb + rowb[t] + cwr) = hi;
        *(uint2*)(Fb + 8192 + rowb[t] + cwr) = lo;
        split4(wi, hi, lo);
        *(uint2*)(Fb + rowb[t] + cwr + 128) = hi;
        *(uint2*)(Fb + 8192 + rowb[t] + cwr + 128) = lo;
    }
}

__device__ __forceinline__ void epi_pow(
    int cwr, const int* rowb, char* Fb, f32x4* acc0, f32x4* acc1)
{
    #pragma unroll
    for (int t = 0; t < 2; ++t) {
        float pw[4];
        #pragma unroll
        for (int r = 0; r < 4; ++r)
            pw[r] = fmaf(acc0[t][r], acc0[t][r], acc1[t][r] * acc1[t][r]);
        uint2 hi, lo;
        split4(pw, hi, lo);
        *(uint2*)(Fb + rowb[t] + cwr) = hi;
        *(uint2*)(Fb + 8192 + rowb[t] + cwr) = lo;
    }
}

__device__ __forceinline__ void epi_relu1(
    const float* __restrict__ b1, int kw, int cwr, const int* rowb,
    char* Fb, f32x4* acc0, f32x4* acc1)
{
    float4 bb0 = *(const float4*)&b1[kw];
    float4 bb1 = *(const float4*)&b1[kw + 64];
    #pragma unroll
    for (int t = 0; t < 2; ++t) {
        float h0[4], h1v[4];
        #pragma unroll
        for (int r = 0; r < 4; ++r) {
            h0[r]  = fmaxf(acc0[t][r] + ((const float*)&bb0)[r], 0.f);
            h1v[r] = fmaxf(acc1[t][r] + ((const float*)&bb1)[r], 0.f);
        }
        uint2 hi, lo;
        split4(h0, hi, lo);
        *(uint2*)(Fb + rowb[t] + cwr) = hi;
        *(uint2*)(Fb + 8192 + rowb[t] + cwr) = lo;
        split4(h1v, hi, lo);
        *(uint2*)(Fb + rowb[t] + cwr + 128) = hi;
        *(uint2*)(Fb + 8192 + rowb[t] + cwr + 128) = lo;
    }
}

__device__ __forceinline__ void epi_relu2(
    const float* __restrict__ b2, int kw, int cwr, const int* rowb,
    char* Fb, f32x4* acc0)
{
    float4 bb = *(const float4*)&b2[kw];
    #pragma unroll
    for (int t = 0; t < 2; ++t) {
        float h[4];
        #pragma unroll
        for (int r = 0; r < 4; ++r)
            h[r] = fmaxf(acc0[t][r] + ((const float*)&bb)[r], 0.f);
        uint2 hi, lo;
        split4(h, hi, lo);
        *(uint2*)(Fb + rowb[t] + cwr) = hi;
        *(uint2*)(Fb + 8192 + rowb[t] + cwr) = lo;
    }
}

// ---------------------------------------------------------------------------
// Kernel 4: main. 64 samples/block as TWO 32-sample buffers, 256 threads
// (4 waves), skewed pipeline: each phase = {MFMA of X} + {epilogue of Y}.
// LDS: FA_h | FA_l | FB_h | FB_l, 4 x 8192 B = 32768 B, XOR-swizzled rows.
// ---------------------------------------------------------------------------
__global__ __launch_bounds__(256, 4) void ficonn_main(
    const float* __restrict__ x,
    const float* __restrict__ b1,
    const float* __restrict__ b2,
    const float* __restrict__ b3,
    const unsigned short* __restrict__ AH,
    const float4* __restrict__ nofuC,
    const float* __restrict__ W3T,
    float* __restrict__ out)
{
    const unsigned short* AL = AH + AH_SHORTS;
    extern __shared__ unsigned short Fdyn[];
    char* FA = (char*)Fdyn;              // hi +0, lo +8192
    char* FB = (char*)Fdyn + 16384;      // hi +0, lo +8192

    const int tid  = threadIdx.x;
    const int lane = tid & 63;
    const int w    = __builtin_amdgcn_readfirstlane(tid >> 6);   // 0..3
    const int mp   = w;
    const int n16  = lane & 15, q = lane >> 4;
    const int base = blockIdx.x * 64;

    // ---- stage x into both buffers (split bf16); input real -> cols 0..127 ----
    {
        const float4* x4 = (const float4*)(x + (size_t)base * 64);
        #pragma unroll
        for (int it = 0; it < 4; ++it) {
            int idx = tid + it * 256;           // 1024 float4 = 64 samples
            int j4 = idx & 15, s = idx >> 4;
            float4 v4 = x4[idx];
            float vv[4] = {v4.x, v4.y, v4.z, v4.w};
            uint2 hi, lo; split4(vv, hi, lo);
            int off = ((s >> 5) << 14) + ((s & 31) << 8) + ((8 * j4) ^ ((s & 7) << 4));
            *(uint2*)((char*)Fdyn + off) = hi;
            *(uint2*)((char*)Fdyn + off + 8192) = lo;
        }
    }
    __syncthreads();

    const int x0 = (n16 & 7) << 4;              // per-lane col XOR (row&7 == n16&7)
    int rowb[2];
    rowb[0] = n16 << 8;
    rowb[1] = (16 + n16) << 8;
    const int kw  = 16 * mp + 4 * q;            // logical output k-base (shorts)
    const int cwr = (32 * mp + 8 * q) ^ x0;     // swizzled byte col for writes

    f32x4 aA0[2], aA1[2], aB0[2], aB1[2];

    // ---- skewed pipeline: A leads by half a stage ----
    // P0
    mm2<2, true>(AH, AL, FA, 0, mp, lane, q, x0, rowb, aA0, aA1);
    __syncthreads();
    // P1
    mm2<2, true>(AH, AL, FB, 0, mp, lane, q, x0, rowb, aB0, aB1);
    epi_nofu(nofuC, 0, kw, cwr, rowb, FA, aA0, aA1);
    __syncthreads();

    #pragma unroll 1
    for (int l = 1; l < 5; ++l) {
        mm2<4, true>(AH, AL, FA, l, mp, lane, q, x0, rowb, aA0, aA1);
        epi_nofu(nofuC, l - 1, kw, cwr, rowb, FB, aB0, aB1);
        __syncthreads();
        mm2<4, true>(AH, AL, FB, l, mp, lane, q, x0, rowb, aB0, aB1);
        if (l < 4) epi_nofu(nofuC, l, kw, cwr, rowb, FA, aA0, aA1);
        else       epi_pow(cwr, rowb, FA, aA0, aA1);
        __syncthreads();
    }

    // W1 (slot 5, K4=2, PAIR)
    mm2<2, true>(AH, AL, FA, 5, mp, lane, q, x0, rowb, aA0, aA1);
    epi_pow(cwr, rowb, FB, aB0, aB1);
    __syncthreads();
    mm2<2, true>(AH, AL, FB, 5, mp, lane, q, x0, rowb, aB0, aB1);
    epi_relu1(b1, kw, cwr, rowb, FA, aA0, aA1);
    __syncthreads();
    // W2 (slot 6, K4=4, no pair)
    mm2<4, false>(AH, AL, FA, 6, mp, lane, q, x0, rowb, aA0, aA1);
    epi_relu1(b1, kw, cwr, rowb, FB, aB0, aB1);
    __syncthreads();
    mm2<4, false>(AH, AL, FB, 6, mp, lane, q, x0, rowb, aB0, aB1);
    epi_relu2(b2, kw, cwr, rowb, FA, aA0);
    __syncthreads();
    epi_relu2(b2, kw, cwr, rowb, FB, aB0);
    __syncthreads();

    // ================= W3: fp32 VALU, 256 threads: (sample, out-triple) ======
    {
        const int n  = tid & 63;
        const int rg = __builtin_amdgcn_readfirstlane(tid >> 6);   // 0..3
        float o0 = b3[3 * rg], o1 = b3[3 * rg + 1], o2 = b3[3 * rg + 2];
        const char* rh = (const char*)Fdyn + ((n >> 5) << 14) + ((n & 31) << 8);
        const char* rl = rh + 8192;
        const int xr = (n & 7) << 4;
        #pragma unroll
        for (int kc = 0; kc < 8; ++kc) {
            int cb = (16 * kc) ^ xr;
            uint4 ph = *(const uint4*)(rh + cb);
            uint4 pl = *(const uint4*)(rl + cb);
            unsigned hu[4] = {ph.x, ph.y, ph.z, ph.w};
            unsigned lu[4] = {pl.x, pl.y, pl.z, pl.w};
            #pragma unroll
            for (int e = 0; e < 4; ++e) {
                int k = 8 * kc + 2 * e;
                float ha = __uint_as_float(hu[e] << 16)
                         + __uint_as_float(lu[e] << 16);
                float hb = __uint_as_float(hu[e] & 0xffff0000u)
                         + __uint_as_float(lu[e] & 0xffff0000u);
                const float* wa = W3T + k * 12 + 3 * rg;
                const float* wb = wa + 12;
                o0 = fmaf(wa[0], ha, fmaf(wb[0], hb, o0));
                o1 = fmaf(wa[1], ha, fmaf(wb[1], hb, o1));
                o2 = fmaf(wa[2], ha, fmaf(wb[2], hb, o2));
            }
        }
        float* op = out + (size_t)(base + n) * 12 + 3 * rg;
        op[0] = o0; op[1] = o1; op[2] = o2;
    }
}

extern "C" void kernel_launch(void* const* d_in, const int* in_sizes, int n_in,
                              void* d_out, int out_size, void* d_ws, size_t ws_size,
                              hipStream_t stream)
{
    const float* x    = (const float*)d_in[0];
    const float* mzi  = (const float*)d_in[1];
    const float* oph  = (const float*)d_in[2];
    const float* beta = (const float*)d_in[3];
    const float* det0 = (const float*)d_in[4];
    const float* W1   = (const float*)d_in[5];
    const float* b1   = (const float*)d_in[6];
    const float* W2   = (const float*)d_in[7];
    const float* b2   = (const float*)d_in[8];
    const float* W3   = (const float*)d_in[9];
    const float* b3   = (const float*)d_in[10];
    float* out = (float*)d_out;

    unsigned short* AH = (unsigned short*)d_ws;
    float* fbase = (float*)((char*)d_ws + FLOAT_BYTE);
    const float4* nofuC = (const float4*)fbase;
    const float* W3T = fbase + 1024;
    float2* Pg = (float2*)((char*)d_ws + PSEG_BYTE);

    const int B = in_sizes[0] / NN;       // 262144
    const int blocks = B / 64;            // 4096
    const size_t main_lds = 32768;        // FA_h|FA_l|FB_h|FB_l x 8 KiB
    const size_t comb_lds = (4u * 4160u + 64u) * sizeof(float2);         // 133632

    hipLaunchKernelGGL(build_seg, dim3(20), dim3(64), 0, stream, mzi, Pg);
    hipLaunchKernelGGL(prep_weights, dim3(68), dim3(256), 0, stream,
                       W1, W2, W3, beta, det0, AH);
    hipLaunchKernelGGL(build_combine, dim3(LL), dim3(256), comb_lds, stream,
                       Pg, oph, AH);
    hipLaunchKernelGGL(ficonn_main, dim3(blocks), dim3(256), main_lds, stream,
                       x, b1, b2, b3, AH, nofuC, W3T, out);
}

// Round 4
// 361.825 us; speedup vs baseline: 1.2040x; 1.2040x over previous
//
#include <hip/hip_runtime.h>
#include <math.h>

// FICONN forward, split-bf16 MFMA (hi+lo, 3-product) + segment-parallel unitary build.
// R10 vs R8 (R9 skew reverted -- it regressed 162->180):
//   Model: MFMA phases are LDS-READ-BW bound: every wave read the FULL F tile
//   (waves split M). Fix: 16x16x32 -> 32x32x16 MFMA. B-frag bytes feed 32 M-rows
//   instead of 16 -> per-wave B LDS reads halve (wave reads only its 32-sample
//   half); matrix cycles -20% (8.07 cyc/32k FLOP vs 2x4.85/2x16k). A-frag global
//   loads double but ride the near-idle VMEM/L2 path. Wave (mh,nh) owns Mt32 pair
//   {mh, mh+2} (rows m / m+64 thread-local for nofu, C/D row=(r&3)+8(r>>2)+4(l>>5))
//   x 32 samples. Phase structure, swizzle, staging, W3 tail identical to R8.

#define NN 64
#define LL 5
#define NMZI 2016
#define C_HALF 0.7071067811865476f
#define GAMMA_ 0.05f
#define SENSRESP 0.0008f     // SENS*RESP

#define AH_SHORTS   114688   // 7 slots * 4 Mt32 * 8 Kt16 * 512 shorts
#define FLOAT_BYTE  458752   // nofuC (1024 f) + W3T (768 f)
#define PSEG_BYTE   466944   // 5l x 4s x 64c x 64r float2 = 655360 B

typedef short short8 __attribute__((ext_vector_type(8)));
typedef float f32x16 __attribute__((ext_vector_type(16)));

union U4S8 { uint4 u; short8 s; };

#define MFMA32(a, b, c) __builtin_amdgcn_mfma_f32_32x32x16_bf16((a), (b), (c), 0, 0, 0)

__device__ __forceinline__ unsigned short f2bf(float f) {
    unsigned u = __float_as_uint(f);
    unsigned r = u + 0x7fffu + ((u >> 16) & 1u);
    return (unsigned short)(r >> 16);
}
__device__ __forceinline__ float bf2f(unsigned short h) {
    return __uint_as_float(((unsigned)h) << 16);
}
// packed bf16 convert: bits[15:0]=bf16(a), bits[31:16]=bf16(b)  (RNE)
__device__ __forceinline__ unsigned cvtpk(float a, float b) {
    unsigned r;
    asm("v_cvt_pk_bf16_f32 %0, %1, %2" : "=v"(r) : "v"(a), "v"(b));
    return r;
}
// split 4 floats into packed-bf16 hi plane + packed-bf16 residual plane.
__device__ __forceinline__ void split4(const float* v, uint2& hi, uint2& lo) {
    hi.x = cvtpk(v[0], v[1]);
    hi.y = cvtpk(v[2], v[3]);
    float l0 = v[0] - __uint_as_float(hi.x << 16);
    float l1 = v[1] - __uint_as_float(hi.x & 0xffff0000u);
    float l2 = v[2] - __uint_as_float(hi.y << 16);
    float l3 = v[3] - __uint_as_float(hi.y & 0xffff0000u);
    lo.x = cvtpk(l0, l1);
    lo.y = cvtpk(l2, l3);
}
// 32x32x16 A-frag linear offset (shorts) of element (m,k) in slot l.
// Lane l: m = l&31, k = 8*(l>>5)+j  ->  lane*8 flat within a 512-short tile.
// Slot = 4 Mt32 x 8 Kt16 tiles = 16384 shorts (same footprint as before).
__device__ __forceinline__ int afrag32_off(int l, int m, int k) {
    return (((l * 4 + (m >> 5)) * 8 + (k >> 4)) << 9)
         + (((k >> 3) & 1) << 8) + ((m & 31) << 3) + (k & 7);
}

// ---------------------------------------------------------------------------
// Kernel 1: build_seg. 20 blocks (layer l, segment s) x 64 threads.
// ---------------------------------------------------------------------------
template<int I0, int I1>
__device__ __forceinline__ void run_scan(const float cs[][4], float* ur, float* ui)
{
    int m = 0;
    #pragma unroll
    for (int i = I0; i < I1; ++i) {
        #pragma unroll
        for (int j = i + 1; j < NN; ++j) {
            float cph = cs[m][0], sph = cs[m][1];
            float cct = cs[m][2], cst = cs[m][3];
            float tr = cph * ur[j] - sph * ui[j];
            float ti = cph * ui[j] + sph * ur[j];
            float ar = ur[i] + tr, ai = ui[i] + ti;
            float sr = ur[i] - tr, si = ui[i] - ti;
            ur[i] = C_HALF * ar;
            ui[i] = C_HALF * ai;
            ur[j] = cct * sr - cst * si;
            ui[j] = cct * si + cst * sr;
            ++m;
        }
    }
}

__global__ __launch_bounds__(64) void build_seg(
    const float* __restrict__ mzi, float2* __restrict__ Pg)
{
    const int b = blockIdx.x;
    const int l = b >> 2, s = b & 3;
    const int c = threadIdx.x;

    __shared__ float cs[531][4];
    const int M0s[5] = {0, 531, 1026, 1488, 2016};
    const int m0 = M0s[s], cnt = M0s[s + 1] - m0;

    for (int t = c; t < cnt; t += 64) {
        int m = m0 + t;
        float th = mzi[l * 2 * NMZI + 2 * m];
        float ph = mzi[l * 2 * NMZI + 2 * m + 1];
        float sth, cth, sph, cph;
        sincosf(th, &sth, &cth);
        sincosf(ph, &sph, &cph);
        cs[t][0] = cph; cs[t][1] = sph;
        cs[t][2] = C_HALF * cth; cs[t][3] = C_HALF * sth;
    }
    __syncthreads();

    float ur[NN], ui[NN];
    #pragma unroll
    for (int r = 0; r < NN; ++r) { ur[r] = (r == c) ? 1.f : 0.f; ui[r] = 0.f; }

    switch (s) {
        case 0: run_scan<0,  9>(cs, ur, ui); break;
        case 1: run_scan<9, 19>(cs, ur, ui); break;
        case 2: run_scan<19,31>(cs, ur, ui); break;
        default:run_scan<31,63>(cs, ur, ui); break;
    }

    // store column-major: Pg[(l*4+s)*4096 + c*64 + r]
    float2* P = Pg + ((size_t)(l * 4 + s) << 12) + (c << 6);
    #pragma unroll
    for (int r = 0; r < NN; ++r) P[r] = make_float2(ur[r], ui[r]);
}

// ---------------------------------------------------------------------------
// Kernel 2: build_combine. 5 blocks x 256 threads.
// ---------------------------------------------------------------------------
__device__ __forceinline__ void cpass(const float2* A, const float2* Bm,
                                      int rq, int c, float2* y)
{
    #pragma unroll
    for (int r = 0; r < 16; ++r) y[r] = make_float2(0.f, 0.f);
    #pragma unroll 2
    for (int k = 0; k < 64; ++k) {
        float2 x = Bm[c * 65 + k];                  // own column, 2-way bank (free)
        #pragma unroll
        for (int r = 0; r < 16; ++r) {
            float2 a = A[k * 65 + 16 * rq + r];     // wave-uniform -> broadcast
            y[r].x = fmaf(a.x, x.x, fmaf(-a.y, x.y, y[r].x));
            y[r].y = fmaf(a.x, x.y, fmaf( a.y, x.x, y[r].y));
        }
    }
}

__device__ __forceinline__ void store_split(unsigned short* AH, unsigned short* AL,
                                            int l, int m, int k, float v)
{
    int o = afrag32_off(l, m, k);
    unsigned short h = f2bf(v);
    AH[o] = h;
    AL[o] = f2bf(v - bf2f(h));
}

__global__ __launch_bounds__(256) void build_combine(
    const float2* __restrict__ Pg, const float* __restrict__ oph,
    unsigned short* __restrict__ AH)
{
    unsigned short* AL = AH + AH_SHORTS;
    extern __shared__ float cl[];
    float2* B0 = (float2*)cl;              // 64 x 65 f2 each
    float2* B1 = B0 + 4160;
    float2* B2 = B1 + 4160;
    float2* B3 = B2 + 4160;
    float2* ocs = B3 + 4160;               // 64 f2

    const int l = blockIdx.x;
    const int tid = threadIdx.x;
    const int rq = tid >> 6, c = tid & 63;

    const float2* Pgl = Pg + ((size_t)l << 14);
    #pragma unroll
    for (int sb = 0; sb < 4; ++sb) {
        float2* Bb = B0 + sb * 4160;
        #pragma unroll
        for (int i = 0; i < 16; ++i) {
            int idx = tid + i * 256;
            Bb[(idx >> 6) * 65 + (idx & 63)] = Pgl[(sb << 12) + idx];
        }
    }
    if (tid < NN) {
        float sp, cp; sincosf(oph[l * NN + tid], &sp, &cp);
        ocs[tid] = make_float2(cp, sp);
    }
    __syncthreads();

    float2 t1[16], t2[16];
    cpass(B1, B0, rq, c, t1);   // T1 = P1*P0
    cpass(B3, B2, rq, c, t2);   // T2 = P3*P2
    __syncthreads();
    #pragma unroll
    for (int r = 0; r < 16; ++r) {
        B0[c * 65 + 16 * rq + r] = t1[r];
        B2[c * 65 + 16 * rq + r] = t2[r];
    }
    __syncthreads();

    float2 u[16];
    cpass(B2, B0, rq, c, u);    // U = T2*T1

    #pragma unroll
    for (int r = 0; r < 16; ++r) {
        int mr = 16 * rq + r;
        float2 oc = ocs[mr];
        float vr = oc.x * u[r].x - oc.y * u[r].y;   // e^{i psi_mr} * U[mr][c]
        float vi = oc.x * u[r].y + oc.y * u[r].x;
        // Mat = [[Ur,-Ui],[Ui,Ur]]
        store_split(AH, AL, l, mr,      c,      vr);
        store_split(AH, AL, l, mr,      c + 64, -vi);
        store_split(AH, AL, l, mr + 64, c,      vi);
        store_split(AH, AL, l, mr + 64, c + 64, vr);
    }
}

// ---------------------------------------------------------------------------
// Kernel 3: W1 -> A-slot 5, W2 -> A-slot 6 (split bf16 frags), W3T, nofu consts.
// ---------------------------------------------------------------------------
__global__ void prep_weights(const float* __restrict__ W1,
                             const float* __restrict__ W2,
                             const float* __restrict__ W3,
                             const float* __restrict__ beta_param,
                             const float* __restrict__ det0,
                             unsigned short* __restrict__ AH)
{
    unsigned short* AL = AH + AH_SHORTS;
    float* fbase = (float*)((char*)AH + FLOAT_BYTE);
    float* nofuF = fbase;               // 1024 floats (256 x float4)
    float* W3T   = fbase + 1024;        // 768 floats

    int idx = blockIdx.x * 256 + threadIdx.x;
    if (idx < 8192) {                        // W1 (128x64)
        int mm = idx >> 6, k = idx & 63;
        float v = W1[idx];
        unsigned short h = f2bf(v);
        int o = afrag32_off(5, mm, k);
        AH[o] = h; AL[o] = f2bf(v - bf2f(h));
    } else if (idx < 16384) {                // W2 (64x128)
        int t = idx - 8192;
        int mm = t >> 7, k = t & 127;
        float v = W2[t];
        unsigned short h = f2bf(v);
        int o = afrag32_off(6, mm, k);
        AH[o] = h; AL[o] = f2bf(v - bf2f(h));
    } else if (idx < 17152) {                // W3 (12x64) -> W3T[j][r]
        int t = idx - 16384;
        int r = t >> 6, j = t & 63;
        W3T[j * 12 + r] = W3[t];
    } else if (idx < 17408) {                // nofu consts, t = l*64+row
        int t = idx - 17152;
        float bp = beta_param[t];
        float beta = 1.f / (1.f + expf(-bp));
        float* p = nofuF + t * 4;
        p[0] = SENSRESP * beta;
        p[1] = sqrtf(fmaxf(1.f - beta, 0.f)) * GAMMA_;
        p[2] = det0[t];
        p[3] = 0.f;
    }
}

// ---------------------------------------------------------------------------
// mm32: acc = A_slot x F over this wave's 32-sample half, 32x32x16 MFMA,
// 3-product split bf16. PAIR: Mt pair {mh, mh+2} (rows m / m+64) -> accA/accB.
// F0: byte base of F (hi plane +0, lo plane +16384). brow: this thread's
// sample-row byte base. cpre = (h2<<4) ^ ((n&7)<<4) read-swizzle pre-term.
// ---------------------------------------------------------------------------
template<int KT, bool PAIR>
__device__ __forceinline__ void mm32(
    const unsigned short* __restrict__ AH, const unsigned short* __restrict__ AL,
    const char* F0, int slot, int mh, int lane, int brow, int cpre,
    f32x16& accA, f32x16& accB)
{
    #pragma unroll
    for (int r = 0; r < 16; ++r) { accA[r] = 0.f; if (PAIR) accB[r] = 0.f; }

    #pragma unroll
    for (int Kt = 0; Kt < KT; ++Kt) {
        const int ta = (((slot * 4 + mh) * 8 + Kt) << 9);
        U4S8 ahA, alA, ahB, alB;
        ahA.u = ((const uint4*)(AH + ta))[lane];
        alA.u = ((const uint4*)(AL + ta))[lane];
        if (PAIR) {
            ahB.u = ((const uint4*)(AH + ta + 8192))[lane];   // Mt mh+2 (= +2*4096 shorts)
            alB.u = ((const uint4*)(AL + ta + 8192))[lane];
        }
        const int cb = (Kt << 5) ^ cpre;
        short8 bh = *(const short8*)(F0 + brow + cb);
        short8 bl = *(const short8*)(F0 + 16384 + brow + cb);
        accA = MFMA32(ahA.s, bh, accA);
        accA = MFMA32(ahA.s, bl, accA);
        accA = MFMA32(alA.s, bh, accA);
        if (PAIR) {
            accB = MFMA32(ahB.s, bh, accB);
            accB = MFMA32(ahB.s, bl, accB);
            accB = MFMA32(alB.s, bh, accB);
        }
    }
}

// ---------------------------------------------------------------------------
// Kernel 4: main. 64 samples/block, 256 threads (4 waves), 4 blocks/CU.
// wave w: mh=w&1 (Mt32 pair {mh,mh+2}), nh=w>>1 (32-sample half).
// Thread: sample n = 32nh + (lane&31); acc reg 4g+j -> row 32mh+8g+4h2+j.
// F: hi|lo planes 64 rows x 256 B each, XOR-swizzled (byte ^ (row&7)<<4).
// ---------------------------------------------------------------------------
__global__ __launch_bounds__(256, 4) void ficonn_main(
    const float* __restrict__ x,
    const float* __restrict__ b1,
    const float* __restrict__ b2,
    const float* __restrict__ b3,
    const unsigned short* __restrict__ AH,
    const float4* __restrict__ nofuC,
    const float* __restrict__ W3T,
    float* __restrict__ out)
{
    const unsigned short* AL = AH + AH_SHORTS;
    extern __shared__ unsigned short Fdyn[];
    char* F0 = (char*)Fdyn;                     // hi plane; lo plane at +16384

    const int tid  = threadIdx.x;
    const int lane = tid & 63;
    const int w    = __builtin_amdgcn_readfirstlane(tid >> 6);   // 0..3
    const int mh   = w & 1, nh = w >> 1;
    const int nloc = lane & 31;                 // sample within half
    const int h2   = lane >> 5;                 // k-subgroup / row-subgroup
    const int base = blockIdx.x * 64;

    // ---- stage x (split bf16, hi/lo planes); input real -> byte cols 0..127 ----
    {
        const float4* x4 = (const float4*)(x + (size_t)base * 64);
        #pragma unroll
        for (int it = 0; it < 4; ++it) {
            int idx = tid + it * 256;           // 1024 float4 = 64 samples
            int j4 = idx & 15, ss = idx >> 4;
            float4 v4 = x4[idx];
            float vv[4] = {v4.x, v4.y, v4.z, v4.w};
            uint2 hi, lo; split4(vv, hi, lo);
            int off = (ss << 8) + ((8 * j4) ^ ((ss & 7) << 4));
            *(uint2*)(F0 + off) = hi;
            *(uint2*)(F0 + 16384 + off) = lo;
        }
    }
    __syncthreads();

    const int brow  = (32 * nh + nloc) << 8;    // this thread's F row (read+write)
    const int x7    = (nloc & 7) << 4;          // row-swizzle XOR (n&7 == nloc&7)
    const int cpre  = (h2 << 4) ^ x7;           // read col pre-term
    const int mrow0 = 32 * mh + 4 * h2;         // row group g starts at mrow0 + 8g

    f32x16 accA, accB;

    // ================= 5 unitary layers =================
    #pragma unroll 1
    for (int l = 0; l < 5; ++l) {
        if (l == 0) mm32<4, true>(AH, AL, F0, 0, mh, lane, brow, cpre, accA, accB);
        else        mm32<8, true>(AH, AL, F0, l, mh, lane, brow, cpre, accA, accB);
        __syncthreads();   // all F reads done

        if (l < 4) {
            #pragma unroll
            for (int g = 0; g < 4; ++g) {
                const int m0 = mrow0 + 8 * g;
                float wr[4], wi[4];
                #pragma unroll
                for (int j = 0; j < 4; ++j) {
                    float yr = accA[4 * g + j], yi = accB[4 * g + j];
                    float4 c = nofuC[l * 64 + m0 + j];
                    float p   = fmaf(yr, yr, yi * yi);
                    float det = fmaf(c.x, p, c.z);
                    float sc  = c.y * __builtin_amdgcn_rcpf(fmaf(det, det, GAMMA_ * GAMMA_));
                    float tr = sc * GAMMA_, ti = sc * det;
                    wr[j] = fmaf(tr, yr,  ti * yi);
                    wi[j] = fmaf(tr, yi, -ti * yr);
                }
                const int cw = (2 * m0) ^ x7;
                uint2 hi, lo;
                split4(wr, hi, lo);
                *(uint2*)(F0 + brow + cw) = hi;
                *(uint2*)(F0 + 16384 + brow + cw) = lo;
                split4(wi, hi, lo);
                *(uint2*)(F0 + brow + cw + 128) = hi;
                *(uint2*)(F0 + 16384 + brow + cw + 128) = lo;
            }
        } else {
            #pragma unroll
            for (int g = 0; g < 4; ++g) {
                const int m0 = mrow0 + 8 * g;
                float pw[4];
                #pragma unroll
                for (int j = 0; j < 4; ++j)
                    pw[j] = fmaf(accA[4 * g + j], accA[4 * g + j],
                                 accB[4 * g + j] * accB[4 * g + j]);
                const int cw = (2 * m0) ^ x7;
                uint2 hi, lo;
                split4(pw, hi, lo);
                *(uint2*)(F0 + brow + cw) = hi;
                *(uint2*)(F0 + 16384 + brow + cw) = lo;
            }
        }
        __syncthreads();
    }

    // ================= W1: M=128, K=64 (slot 5), Mt pair {mh, mh+2} ==========
    {
        mm32<4, true>(AH, AL, F0, 5, mh, lane, brow, cpre, accA, accB);
        __syncthreads();

        #pragma unroll
        for (int g = 0; g < 4; ++g) {
            const int m0 = mrow0 + 8 * g;
            float4 bba = *(const float4*)&b1[m0];
            float4 bbb = *(const float4*)&b1[m0 + 64];
            float h0[4], h1v[4];
            #pragma unroll
            for (int j = 0; j < 4; ++j) {
                h0[j]  = fmaxf(accA[4 * g + j] + ((const float*)&bba)[j], 0.f);
                h1v[j] = fmaxf(accB[4 * g + j] + ((const float*)&bbb)[j], 0.f);
            }
            const int cw = (2 * m0) ^ x7;
            uint2 hi, lo;
            split4(h0, hi, lo);
            *(uint2*)(F0 + brow + cw) = hi;
            *(uint2*)(F0 + 16384 + brow + cw) = lo;
            split4(h1v, hi, lo);
            *(uint2*)(F0 + brow + cw + 128) = hi;
            *(uint2*)(F0 + 16384 + brow + cw + 128) = lo;
        }
        __syncthreads();
    }

    // ================= W2: M=64, K=128 (slot 6), single Mt = mh ==============
    {
        mm32<8, false>(AH, AL, F0, 6, mh, lane, brow, cpre, accA, accB);
        __syncthreads();

        #pragma unroll
        for (int g = 0; g < 4; ++g) {
            const int m0 = mrow0 + 8 * g;
            float4 bb = *(const float4*)&b2[m0];
            float h[4];
            #pragma unroll
            for (int j = 0; j < 4; ++j)
                h[j] = fmaxf(accA[4 * g + j] + ((const float*)&bb)[j], 0.f);
            const int cw = (2 * m0) ^ x7;
            uint2 hi, lo;
            split4(h, hi, lo);
            *(uint2*)(F0 + brow + cw) = hi;
            *(uint2*)(F0 + 16384 + brow + cw) = lo;
        }
        __syncthreads();
    }

    // ================= W3: fp32 VALU, 256 threads: (sample, out-triple) ======
    {
        const int n  = tid & 63;
        const int rg = __builtin_amdgcn_readfirstlane(tid >> 6);   // 0..3
        float o0 = b3[3 * rg], o1 = b3[3 * rg + 1], o2 = b3[3 * rg + 2];
        const char* rh = F0 + (n << 8);
        const char* rl = rh + 16384;
        const int xr = (n & 7) << 4;
        #pragma unroll
        for (int kc = 0; kc < 8; ++kc) {
            int cb = (16 * kc) ^ xr;
            uint4 ph = *(const uint4*)(rh + cb);
            uint4 pl = *(const uint4*)(rl + cb);
            unsigned hu[4] = {ph.x, ph.y, ph.z, ph.w};
            unsigned lu[4] = {pl.x, pl.y, pl.z, pl.w};
            #pragma unroll
            for (int e = 0; e < 4; ++e) {
                int k = 8 * kc + 2 * e;
                float ha = __uint_as_float(hu[e] << 16)
                         + __uint_as_float(lu[e] << 16);
                float hb = __uint_as_float(hu[e] & 0xffff0000u)
                         + __uint_as_float(lu[e] & 0xffff0000u);
                const float* wa = W3T + k * 12 + 3 * rg;
                const float* wb = wa + 12;
                o0 = fmaf(wa[0], ha, fmaf(wb[0], hb, o0));
                o1 = fmaf(wa[1], ha, fmaf(wb[1], hb, o1));
                o2 = fmaf(wa[2], ha, fmaf(wb[2], hb, o2));
            }
        }
        float* op = out + (size_t)(base + n) * 12 + 3 * rg;
        op[0] = o0; op[1] = o1; op[2] = o2;
    }
}

extern "C" void kernel_launch(void* const* d_in, const int* in_sizes, int n_in,
                              void* d_out, int out_size, void* d_ws, size_t ws_size,
                              hipStream_t stream)
{
    const float* x    = (const float*)d_in[0];
    const float* mzi  = (const float*)d_in[1];
    const float* oph  = (const float*)d_in[2];
    const float* beta = (const float*)d_in[3];
    const float* det0 = (const float*)d_in[4];
    const float* W1   = (const float*)d_in[5];
    const float* b1   = (const float*)d_in[6];
    const float* W2   = (const float*)d_in[7];
    const float* b2   = (const float*)d_in[8];
    const float* W3   = (const float*)d_in[9];
    const float* b3   = (const float*)d_in[10];
    float* out = (float*)d_out;

    unsigned short* AH = (unsigned short*)d_ws;
    float* fbase = (float*)((char*)d_ws + FLOAT_BYTE);
    const float4* nofuC = (const float4*)fbase;
    const float* W3T = fbase + 1024;
    float2* Pg = (float2*)((char*)d_ws + PSEG_BYTE);

    const int B = in_sizes[0] / NN;       // 262144
    const int blocks = B / 64;            // 4096
    const size_t main_lds = 32768;        // hi|lo planes, 2 x 16384 B (swizzled)
    const size_t comb_lds = (4u * 4160u + 64u) * sizeof(float2);         // 133632

    hipLaunchKernelGGL(build_seg, dim3(20), dim3(64), 0, stream, mzi, Pg);
    hipLaunchKernelGGL(prep_weights, dim3(68), dim3(256), 0, stream,
                       W1, W2, W3, beta, det0, AH);
    hipLaunchKernelGGL(build_combine, dim3(LL), dim3(256), comb_lds, stream,
                       Pg, oph, AH);
    hipLaunchKernelGGL(ficonn_main, dim3(blocks), dim3(256), main_lds, stream,
                       x, b1, b2, b3, AH, nofuC, W3T, out);
}

// Round 6
// 349.183 us; speedup vs baseline: 1.2476x; 1.0362x over previous
//
#include <hip/hip_runtime.h>
#include <math.h>

// FICONN forward, split-bf16 MFMA (hi+lo, 3-product) + segment-parallel unitary build.
// R12 = R11 with the W3-tail bug fixed: rg = tid>>5 is NOT wave-uniform, so
// readfirstlane(tid>>5) collapsed lanes 32-63 to the wrong out-triple (rg 1,3
// never written -> absmax 9e-3). Per-lane rg now. Structure unchanged vs R11:
//   R8 16x16x32 core (8 indep acc chains) + DOUBLE-BUFFERED F, 32 samples/block,
//   4 waves, one barrier per phase: mm reads F_cur, epilogue writes F_nxt,
//   barrier, swap. Barriers 15 -> 8; epilogue VALU of one wave overlaps sibling
//   waves' MFMA within a phase. Per-sample math bit-identical to R8.

#define NN 64
#define LL 5
#define NMZI 2016
#define C_HALF 0.7071067811865476f
#define GAMMA_ 0.05f
#define SENSRESP 0.0008f     // SENS*RESP

#define AH_SHORTS   114688   // 7 slots * 8Mt * 4Kt * 512 shorts
#define FLOAT_BYTE  458752   // nofuC (1024 f) + W3T (768 f)
#define PSEG_BYTE   466944   // 5l x 4s x 64c x 64r float2 = 655360 B

typedef short short8 __attribute__((ext_vector_type(8)));
typedef float f32x4  __attribute__((ext_vector_type(4)));

union U4S8 { uint4 u; short8 s; };

#define MFMA16(a, b, c) __builtin_amdgcn_mfma_f32_16x16x32_bf16((a), (b), (c), 0, 0, 0)

__device__ __forceinline__ unsigned short f2bf(float f) {
    unsigned u = __float_as_uint(f);
    unsigned r = u + 0x7fffu + ((u >> 16) & 1u);
    return (unsigned short)(r >> 16);
}
__device__ __forceinline__ float bf2f(unsigned short h) {
    return __uint_as_float(((unsigned)h) << 16);
}
// packed bf16 convert: bits[15:0]=bf16(a), bits[31:16]=bf16(b)  (RNE)
__device__ __forceinline__ unsigned cvtpk(float a, float b) {
    unsigned r;
    asm("v_cvt_pk_bf16_f32 %0, %1, %2" : "=v"(r) : "v"(a), "v"(b));
    return r;
}
// split 4 floats into packed-bf16 hi plane + packed-bf16 residual plane.
__device__ __forceinline__ void split4(const float* v, uint2& hi, uint2& lo) {
    hi.x = cvtpk(v[0], v[1]);
    hi.y = cvtpk(v[2], v[3]);
    float l0 = v[0] - __uint_as_float(hi.x << 16);
    float l1 = v[1] - __uint_as_float(hi.x & 0xffff0000u);
    float l2 = v[2] - __uint_as_float(hi.y << 16);
    float l3 = v[3] - __uint_as_float(hi.y & 0xffff0000u);
    lo.x = cvtpk(l0, l1);
    lo.y = cvtpk(l2, l3);
}
// frag-linear offset (in shorts) of element (m,k) of A-slot l (16x16x32 layout)
__device__ __forceinline__ int afrag_off(int l, int m, int k) {
    return ((((l * 8 + (m >> 4)) * 4 + (k >> 5)) << 9)
          + ((((k >> 3) & 3) * 16 + (m & 15)) << 3) + (k & 7));
}

// ---------------------------------------------------------------------------
// Kernel 1: build_seg. 20 blocks (layer l, segment s) x 64 threads.
// ---------------------------------------------------------------------------
template<int I0, int I1>
__device__ __forceinline__ void run_scan(const float cs[][4], float* ur, float* ui)
{
    int m = 0;
    #pragma unroll
    for (int i = I0; i < I1; ++i) {
        #pragma unroll
        for (int j = i + 1; j < NN; ++j) {
            float cph = cs[m][0], sph = cs[m][1];
            float cct = cs[m][2], cst = cs[m][3];
            float tr = cph * ur[j] - sph * ui[j];
            float ti = cph * ui[j] + sph * ur[j];
            float ar = ur[i] + tr, ai = ui[i] + ti;
            float sr = ur[i] - tr, si = ui[i] - ti;
            ur[i] = C_HALF * ar;
            ui[i] = C_HALF * ai;
            ur[j] = cct * sr - cst * si;
            ui[j] = cct * si + cst * sr;
            ++m;
        }
    }
}

__global__ __launch_bounds__(64) void build_seg(
    const float* __restrict__ mzi, float2* __restrict__ Pg)
{
    const int b = blockIdx.x;
    const int l = b >> 2, s = b & 3;
    const int c = threadIdx.x;

    __shared__ float cs[531][4];
    const int M0s[5] = {0, 531, 1026, 1488, 2016};
    const int m0 = M0s[s], cnt = M0s[s + 1] - m0;

    for (int t = c; t < cnt; t += 64) {
        int m = m0 + t;
        float th = mzi[l * 2 * NMZI + 2 * m];
        float ph = mzi[l * 2 * NMZI + 2 * m + 1];
        float sth, cth, sph, cph;
        sincosf(th, &sth, &cth);
        sincosf(ph, &sph, &cph);
        cs[t][0] = cph; cs[t][1] = sph;
        cs[t][2] = C_HALF * cth; cs[t][3] = C_HALF * sth;
    }
    __syncthreads();

    float ur[NN], ui[NN];
    #pragma unroll
    for (int r = 0; r < NN; ++r) { ur[r] = (r == c) ? 1.f : 0.f; ui[r] = 0.f; }

    switch (s) {
        case 0: run_scan<0,  9>(cs, ur, ui); break;
        case 1: run_scan<9, 19>(cs, ur, ui); break;
        case 2: run_scan<19,31>(cs, ur, ui); break;
        default:run_scan<31,63>(cs, ur, ui); break;
    }

    // store column-major: Pg[(l*4+s)*4096 + c*64 + r]
    float2* P = Pg + ((size_t)(l * 4 + s) << 12) + (c << 6);
    #pragma unroll
    for (int r = 0; r < NN; ++r) P[r] = make_float2(ur[r], ui[r]);
}

// ---------------------------------------------------------------------------
// Kernel 2: build_combine. 5 blocks x 256 threads.
// ---------------------------------------------------------------------------
__device__ __forceinline__ void cpass(const float2* A, const float2* Bm,
                                      int rq, int c, float2* y)
{
    #pragma unroll
    for (int r = 0; r < 16; ++r) y[r] = make_float2(0.f, 0.f);
    #pragma unroll 2
    for (int k = 0; k < 64; ++k) {
        float2 x = Bm[c * 65 + k];                  // own column, 2-way bank (free)
        #pragma unroll
        for (int r = 0; r < 16; ++r) {
            float2 a = A[k * 65 + 16 * rq + r];     // wave-uniform -> broadcast
            y[r].x = fmaf(a.x, x.x, fmaf(-a.y, x.y, y[r].x));
            y[r].y = fmaf(a.x, x.y, fmaf( a.y, x.x, y[r].y));
        }
    }
}

__device__ __forceinline__ void store_split(unsigned short* AH, unsigned short* AL,
                                            int l, int m, int k, float v)
{
    int o = afrag_off(l, m, k);
    unsigned short h = f2bf(v);
    AH[o] = h;
    AL[o] = f2bf(v - bf2f(h));
}

__global__ __launch_bounds__(256) void build_combine(
    const float2* __restrict__ Pg, const float* __restrict__ oph,
    unsigned short* __restrict__ AH)
{
    unsigned short* AL = AH + AH_SHORTS;
    extern __shared__ float cl[];
    float2* B0 = (float2*)cl;              // 64 x 65 f2 each
    float2* B1 = B0 + 4160;
    float2* B2 = B1 + 4160;
    float2* B3 = B2 + 4160;
    float2* ocs = B3 + 4160;               // 64 f2

    const int l = blockIdx.x;
    const int tid = threadIdx.x;
    const int rq = tid >> 6, c = tid & 63;

    const float2* Pgl = Pg + ((size_t)l << 14);
    #pragma unroll
    for (int sb = 0; sb < 4; ++sb) {
        float2* Bb = B0 + sb * 4160;
        #pragma unroll
        for (int i = 0; i < 16; ++i) {
            int idx = tid + i * 256;
            Bb[(idx >> 6) * 65 + (idx & 63)] = Pgl[(sb << 12) + idx];
        }
    }
    if (tid < NN) {
        float sp, cp; sincosf(oph[l * NN + tid], &sp, &cp);
        ocs[tid] = make_float2(cp, sp);
    }
    __syncthreads();

    float2 t1[16], t2[16];
    cpass(B1, B0, rq, c, t1);   // T1 = P1*P0
    cpass(B3, B2, rq, c, t2);   // T2 = P3*P2
    __syncthreads();
    #pragma unroll
    for (int r = 0; r < 16; ++r) {
        B0[c * 65 + 16 * rq + r] = t1[r];
        B2[c * 65 + 16 * rq + r] = t2[r];
    }
    __syncthreads();

    float2 u[16];
    cpass(B2, B0, rq, c, u);    // U = T2*T1

    #pragma unroll
    for (int r = 0; r < 16; ++r) {
        int mr = 16 * rq + r;
        float2 oc = ocs[mr];
        float vr = oc.x * u[r].x - oc.y * u[r].y;   // e^{i psi_mr} * U[mr][c]
        float vi = oc.x * u[r].y + oc.y * u[r].x;
        // Mat = [[Ur,-Ui],[Ui,Ur]]
        store_split(AH, AL, l, mr,      c,      vr);
        store_split(AH, AL, l, mr,      c + 64, -vi);
        store_split(AH, AL, l, mr + 64, c,      vi);
        store_split(AH, AL, l, mr + 64, c + 64, vr);
    }
}

// ---------------------------------------------------------------------------
// Kernel 3: W1 -> A-slot 5, W2 -> A-slot 6 (split bf16 frags), W3T, nofu consts.
// ---------------------------------------------------------------------------
__global__ void prep_weights(const float* __restrict__ W1,
                             const float* __restrict__ W2,
                             const float* __restrict__ W3,
                             const float* __restrict__ beta_param,
                             const float* __restrict__ det0,
                             unsigned short* __restrict__ AH)
{
    unsigned short* AL = AH + AH_SHORTS;
    float* fbase = (float*)((char*)AH + FLOAT_BYTE);
    float* nofuF = fbase;               // 1024 floats (256 x float4)
    float* W3T   = fbase + 1024;        // 768 floats

    int idx = blockIdx.x * 256 + threadIdx.x;
    if (idx < 8192) {                        // W1 (128x64)
        int mm = idx >> 6, k = idx & 63;
        float v = W1[idx];
        unsigned short h = f2bf(v);
        int o = afrag_off(5, mm, k);
        AH[o] = h; AL[o] = f2bf(v - bf2f(h));
    } else if (idx < 16384) {                // W2 (64x128)
        int t = idx - 8192;
        int mm = t >> 7, k = t & 127;
        float v = W2[t];
        unsigned short h = f2bf(v);
        int o = afrag_off(6, mm, k);
        AH[o] = h; AL[o] = f2bf(v - bf2f(h));
    } else if (idx < 17152) {                // W3 (12x64) -> W3T[j][r]
        int t = idx - 16384;
        int r = t >> 6, j = t & 63;
        W3T[j * 12 + r] = W3[t];
    } else if (idx < 17408) {                // nofu consts, t = l*64+row
        int t = idx - 17152;
        float bp = beta_param[t];
        float beta = 1.f / (1.f + expf(-bp));
        float* p = nofuF + t * 4;
        p[0] = SENSRESP * beta;
        p[1] = sqrtf(fmaxf(1.f - beta, 0.f)) * GAMMA_;
        p[2] = det0[t];
        p[3] = 0.f;
    }
}

// ---------------------------------------------------------------------------
// mm_block: acc[t] = A_slot x F_cur over 2 N-tiles (32 samples), 16x16x32,
// 3-product split bf16, 8 independent MFMA chains. PAIR: Mt0+4 into acc1.
// Fc: byte base of current buffer (hi +0, lo +8192).
// ---------------------------------------------------------------------------
template<int K4, bool PAIR>
__device__ __forceinline__ void mm_block(
    const unsigned short* __restrict__ AH, const unsigned short* __restrict__ AL,
    const char* Fc, int slot, int mp, int lane, int q, int x7, const int* rowb,
    f32x4* acc0, f32x4* acc1)
{
    #pragma unroll
    for (int t = 0; t < 2; ++t)
        #pragma unroll
        for (int r = 0; r < 4; ++r) { acc0[t][r] = 0.f; if (PAIR) acc1[t][r] = 0.f; }

    #pragma unroll
    for (int Kt = 0; Kt < K4; ++Kt) {
        int off0 = (((slot * 8 + mp) * 4 + Kt) << 9);
        U4S8 ah0, al0, ah1, al1;
        ah0.u = ((const uint4*)(AH + off0))[lane];
        al0.u = ((const uint4*)(AL + off0))[lane];
        if (PAIR) {
            ah1.u = ((const uint4*)(AH + off0 + 8192))[lane];   // Mt0+4
            al1.u = ((const uint4*)(AL + off0 + 8192))[lane];
        }
        const int cb = (64 * Kt + 16 * q) ^ x7;
        #pragma unroll
        for (int t = 0; t < 2; ++t) {
            short8 bh = *(const short8*)(Fc + rowb[t] + cb);
            short8 bl = *(const short8*)(Fc + 8192 + rowb[t] + cb);
            acc0[t] = MFMA16(ah0.s, bh, acc0[t]);
            acc0[t] = MFMA16(ah0.s, bl, acc0[t]);
            acc0[t] = MFMA16(al0.s, bh, acc0[t]);
            if (PAIR) {
                acc1[t] = MFMA16(ah1.s, bh, acc1[t]);
                acc1[t] = MFMA16(ah1.s, bl, acc1[t]);
                acc1[t] = MFMA16(al1.s, bh, acc1[t]);
            }
        }
    }
}

// ---------------------------------------------------------------------------
// Kernel 4: main. 32 samples/block, 256 threads (4 waves), 4 blocks/CU.
// Double-buffered F: buf b at Fdyn + b*16384 (hi +0, lo +8192), 16 KB each,
// 32 rows x 256 B, XOR-swizzled (byte ^ (row&7)<<4). One barrier per phase:
// mm reads F_cur, epilogue writes F_nxt, barrier publishes, swap.
// wave w = mp owns Mt pair {mp, mp+4}; thread (n16,q); t-tiles = 2.
// ---------------------------------------------------------------------------
__global__ __launch_bounds__(256, 4) void ficonn_main(
    const float* __restrict__ x,
    const float* __restrict__ b1,
    const float* __restrict__ b2,
    const float* __restrict__ b3,
    const unsigned short* __restrict__ AH,
    const float4* __restrict__ nofuC,
    const float* __restrict__ W3T,
    float* __restrict__ out)
{
    const unsigned short* AL = AH + AH_SHORTS;
    extern __shared__ unsigned short Fdyn[];
    char* Fc = (char*)Fdyn;              // current buffer
    char* Fn = (char*)Fdyn + 16384;      // next buffer

    const int tid  = threadIdx.x;
    const int lane = tid & 63;
    const int w    = __builtin_amdgcn_readfirstlane(tid >> 6);   // 0..3 (wave-uniform)
    const int mp   = w;
    const int n16  = lane & 15, q = lane >> 4;
    const int base = blockIdx.x * 32;

    // ---- stage x into F_cur (split bf16); input real -> byte cols 0..127 ----
    {
        const float4* x4 = (const float4*)(x + (size_t)base * 64);
        #pragma unroll
        for (int it = 0; it < 2; ++it) {
            int idx = tid + it * 256;           // 512 float4 = 32 samples
            int j4 = idx & 15, ss = idx >> 4;
            float4 v4 = x4[idx];
            float vv[4] = {v4.x, v4.y, v4.z, v4.w};
            uint2 hi, lo; split4(vv, hi, lo);
            int off = (ss << 8) + ((8 * j4) ^ ((ss & 7) << 4));
            *(uint2*)(Fc + off) = hi;
            *(uint2*)(Fc + 8192 + off) = lo;
        }
    }
    __syncthreads();

    const int x7 = (n16 & 7) << 4;              // per-lane col XOR (row&7 == n16&7)
    int rowb[2];
    rowb[0] = n16 << 8;
    rowb[1] = (16 + n16) << 8;
    const int kw  = 16 * mp + 4 * q;            // logical output k-base (shorts)
    const int cwr = (32 * mp + 8 * q) ^ x7;     // swizzled byte col for writes

    f32x4 acc0[2], acc1[2];

    // ================= 5 unitary layers (one barrier each) =================
    #pragma unroll 1
    for (int l = 0; l < 5; ++l) {
        if (l == 0) mm_block<2, true>(AH, AL, Fc, 0, mp, lane, q, x7, rowb, acc0, acc1);
        else        mm_block<4, true>(AH, AL, Fc, l, mp, lane, q, x7, rowb, acc0, acc1);

        if (l < 4) {
            float4 nc[4];
            #pragma unroll
            for (int r = 0; r < 4; ++r) nc[r] = nofuC[l * 64 + kw + r];
            #pragma unroll
            for (int t = 0; t < 2; ++t) {
                float wr[4], wi[4];
                #pragma unroll
                for (int r = 0; r < 4; ++r) {
                    float yr = acc0[t][r], yi = acc1[t][r];
                    float4 c = nc[r];
                    float p   = fmaf(yr, yr, yi * yi);
                    float det = fmaf(c.x, p, c.z);
                    float sc  = c.y * __builtin_amdgcn_rcpf(fmaf(det, det, GAMMA_ * GAMMA_));
                    float tr = sc * GAMMA_, ti = sc * det;
                    wr[r] = fmaf(tr, yr,  ti * yi);
                    wi[r] = fmaf(tr, yi, -ti * yr);
                }
                uint2 hi, lo;
                split4(wr, hi, lo);
                *(uint2*)(Fn + rowb[t] + cwr) = hi;
                *(uint2*)(Fn + 8192 + rowb[t] + cwr) = lo;
                split4(wi, hi, lo);
                *(uint2*)(Fn + rowb[t] + cwr + 128) = hi;
                *(uint2*)(Fn + 8192 + rowb[t] + cwr + 128) = lo;
            }
        } else {
            #pragma unroll
            for (int t = 0; t < 2; ++t) {
                float pw[4];
                #pragma unroll
                for (int r = 0; r < 4; ++r)
                    pw[r] = fmaf(acc0[t][r], acc0[t][r], acc1[t][r] * acc1[t][r]);
                uint2 hi, lo;
                split4(pw, hi, lo);
                *(uint2*)(Fn + rowb[t] + cwr) = hi;
                *(uint2*)(Fn + 8192 + rowb[t] + cwr) = lo;
            }
        }
        __syncthreads();
        char* tmp = Fc; Fc = Fn; Fn = tmp;
    }

    // ================= W1: M=128, K=64 (slot 5), Mt pair {mp, mp+4} ==========
    {
        mm_block<2, true>(AH, AL, Fc, 5, mp, lane, q, x7, rowb, acc0, acc1);

        float4 bb0 = *(const float4*)&b1[kw];
        float4 bb1 = *(const float4*)&b1[kw + 64];
        #pragma unroll
        for (int t = 0; t < 2; ++t) {
            float h0[4], h1v[4];
            #pragma unroll
            for (int r = 0; r < 4; ++r) {
                h0[r]  = fmaxf(acc0[t][r] + ((const float*)&bb0)[r], 0.f);
                h1v[r] = fmaxf(acc1[t][r] + ((const float*)&bb1)[r], 0.f);
            }
            uint2 hi, lo;
            split4(h0, hi, lo);
            *(uint2*)(Fn + rowb[t] + cwr) = hi;
            *(uint2*)(Fn + 8192 + rowb[t] + cwr) = lo;
            split4(h1v, hi, lo);
            *(uint2*)(Fn + rowb[t] + cwr + 128) = hi;
            *(uint2*)(Fn + 8192 + rowb[t] + cwr + 128) = lo;
        }
        __syncthreads();
        char* tmp = Fc; Fc = Fn; Fn = tmp;
    }

    // ================= W2: M=64, K=128 (slot 6), Mt=mp =======================
    {
        mm_block<4, false>(AH, AL, Fc, 6, mp, lane, q, x7, rowb, acc0, acc1);

        float4 bb = *(const float4*)&b2[kw];
        #pragma unroll
        for (int t = 0; t < 2; ++t) {
            float h[4];
            #pragma unroll
            for (int r = 0; r < 4; ++r)
                h[r] = fmaxf(acc0[t][r] + ((const float*)&bb)[r], 0.f);
            uint2 hi, lo;
            split4(h, hi, lo);
            *(uint2*)(Fn + rowb[t] + cwr) = hi;
            *(uint2*)(Fn + 8192 + rowb[t] + cwr) = lo;
        }
        __syncthreads();
        char* tmp = Fc; Fc = Fn; Fn = tmp;
    }

    // ================= W3: fp32 VALU, threads 0..127: (sample, out-triple) ===
    if (tid < 128) {
        const int n  = tid & 31;
        const int rg = tid >> 5;            // 0..3 -- PER-LANE, not wave-uniform!
        float o0 = b3[3 * rg], o1 = b3[3 * rg + 1], o2 = b3[3 * rg + 2];
        const char* rh = Fc + (n << 8);
        const char* rl = rh + 8192;
        const int xr = (n & 7) << 4;
        #pragma unroll
        for (int kc = 0; kc < 8; ++kc) {
            int cb = (16 * kc) ^ xr;
            uint4 ph = *(const uint4*)(rh + cb);
            uint4 pl = *(const uint4*)(rl + cb);
            unsigned hu[4] = {ph.x, ph.y, ph.z, ph.w};
            unsigned lu[4] = {pl.x, pl.y, pl.z, pl.w};
            #pragma unroll
            for (int e = 0; e < 4; ++e) {
                int k = 8 * kc + 2 * e;
                float ha = __uint_as_float(hu[e] << 16)
                         + __uint_as_float(lu[e] << 16);
                float hb = __uint_as_float(hu[e] & 0xffff0000u)
                         + __uint_as_float(lu[e] & 0xffff0000u);
                const float* wa = W3T + k * 12 + 3 * rg;
                const float* wb = wa + 12;
                o0 = fmaf(wa[0], ha, fmaf(wb[0], hb, o0));
                o1 = fmaf(wa[1], ha, fmaf(wb[1], hb, o1));
                o2 = fmaf(wa[2], ha, fmaf(wb[2], hb, o2));
            }
        }
        float* op = out + (size_t)(base + n) * 12 + 3 * rg;
        op[0] = o0; op[1] = o1; op[2] = o2;
    }
}

extern "C" void kernel_launch(void* const* d_in, const int* in_sizes, int n_in,
                              void* d_out, int out_size, void* d_ws, size_t ws_size,
                              hipStream_t stream)
{
    const float* x    = (const float*)d_in[0];
    const float* mzi  = (const float*)d_in[1];
    const float* oph  = (const float*)d_in[2];
    const float* beta = (const float*)d_in[3];
    const float* det0 = (const float*)d_in[4];
    const float* W1   = (const float*)d_in[5];
    const float* b1   = (const float*)d_in[6];
    const float* W2   = (const float*)d_in[7];
    const float* b2   = (const float*)d_in[8];
    const float* W3   = (const float*)d_in[9];
    const float* b3   = (const float*)d_in[10];
    float* out = (float*)d_out;

    unsigned short* AH = (unsigned short*)d_ws;
    float* fbase = (float*)((char*)d_ws + FLOAT_BYTE);
    const float4* nofuC = (const float4*)fbase;
    const float* W3T = fbase + 1024;
    float2* Pg = (float2*)((char*)d_ws + PSEG_BYTE);

    const int B = in_sizes[0] / NN;       // 262144
    const int blocks = B / 32;            // 8192
    const size_t main_lds = 32768;        // 2 buffers x (hi 8K + lo 8K)
    const size_t comb_lds = (4u * 4160u + 64u) * sizeof(float2);         // 133632

    hipLaunchKernelGGL(build_seg, dim3(20), dim3(64), 0, stream, mzi, Pg);
    hipLaunchKernelGGL(prep_weights, dim3(68), dim3(256), 0, stream,
                       W1, W2, W3, beta, det0, AH);
    hipLaunchKernelGGL(build_combine, dim3(LL), dim3(256), comb_lds, stream,
                       Pg, oph, AH);
    hipLaunchKernelGGL(ficonn_main, dim3(blocks), dim3(256), main_lds, stream,
                       x, b1, b2, b3, AH, nofuC, W3T, out);
}

// Round 7
// 323.030 us; speedup vs baseline: 1.3486x; 1.0810x over previous
//
#include <hip/hip_runtime.h>
#include <math.h>

// FICONN forward, split-bf16 MFMA (hi+lo, 3-product).
// R13: main reverted to R8 verbatim (162us proven; R9/R12 overlap variants lost
// more to MFMA-ILP than they gained). New: ALL build work fused into ONE kernel
// (build_all, 73 blocks): blocks 0-4 = per-layer {sincos->cs LDS scratch; 4 waves
// scan 4 segments in registers; P written directly to padded combine buffers --
// Pg global roundtrip deleted; 3 cpasses; A-frag store}, blocks 5-72 = weight
// prep. Launches 4 -> 2. Diagnostic: delta(total)-delta(main) = real build cost.

#define NN 64
#define LL 5
#define NMZI 2016
#define C_HALF 0.7071067811865476f
#define GAMMA_ 0.05f
#define SENSRESP 0.0008f     // SENS*RESP

#define AH_SHORTS   114688   // 7 slots * 8Mt * 4Kt * 512 shorts
#define FLOAT_BYTE  458752   // nofuC (1024 f) + W3T (768 f)

typedef short short8 __attribute__((ext_vector_type(8)));
typedef float f32x4  __attribute__((ext_vector_type(4)));

union U4S8 { uint4 u; short8 s; };

#define MFMA16(a, b, c) __builtin_amdgcn_mfma_f32_16x16x32_bf16((a), (b), (c), 0, 0, 0)

__device__ __forceinline__ unsigned short f2bf(float f) {
    unsigned u = __float_as_uint(f);
    unsigned r = u + 0x7fffu + ((u >> 16) & 1u);
    return (unsigned short)(r >> 16);
}
__device__ __forceinline__ float bf2f(unsigned short h) {
    return __uint_as_float(((unsigned)h) << 16);
}
// packed bf16 convert: bits[15:0]=bf16(a), bits[31:16]=bf16(b)  (RNE)
__device__ __forceinline__ unsigned cvtpk(float a, float b) {
    unsigned r;
    asm("v_cvt_pk_bf16_f32 %0, %1, %2" : "=v"(r) : "v"(a), "v"(b));
    return r;
}
// split 4 floats into packed-bf16 hi plane + packed-bf16 residual plane.
__device__ __forceinline__ void split4(const float* v, uint2& hi, uint2& lo) {
    hi.x = cvtpk(v[0], v[1]);
    hi.y = cvtpk(v[2], v[3]);
    float l0 = v[0] - __uint_as_float(hi.x << 16);
    float l1 = v[1] - __uint_as_float(hi.x & 0xffff0000u);
    float l2 = v[2] - __uint_as_float(hi.y << 16);
    float l3 = v[3] - __uint_as_float(hi.y & 0xffff0000u);
    lo.x = cvtpk(l0, l1);
    lo.y = cvtpk(l2, l3);
}
// frag-linear offset (in shorts) of element (m,k) of A-slot l (16x16x32 layout)
__device__ __forceinline__ int afrag_off(int l, int m, int k) {
    return ((((l * 8 + (m >> 4)) * 4 + (k >> 5)) << 9)
          + ((((k >> 3) & 3) * 16 + (m & 15)) << 3) + (k & 7));
}

// ---------------------------------------------------------------------------
// scan: exact R4-proven register scan over one segment's MZI steps.
// ---------------------------------------------------------------------------
template<int I0, int I1>
__device__ __forceinline__ void run_scan(const float cs[][4], float* ur, float* ui)
{
    int m = 0;
    #pragma unroll
    for (int i = I0; i < I1; ++i) {
        #pragma unroll
        for (int j = i + 1; j < NN; ++j) {
            float cph = cs[m][0], sph = cs[m][1];
            float cct = cs[m][2], cst = cs[m][3];
            float tr = cph * ur[j] - sph * ui[j];
            float ti = cph * ui[j] + sph * ur[j];
            float ar = ur[i] + tr, ai = ui[i] + ti;
            float sr = ur[i] - tr, si = ui[i] - ti;
            ur[i] = C_HALF * ar;
            ui[i] = C_HALF * ai;
            ur[j] = cct * sr - cst * si;
            ui[j] = cct * si + cst * sr;
            ++m;
        }
    }
}

__device__ __forceinline__ void cpass(const float2* A, const float2* Bm,
                                      int rq, int c, float2* y)
{
    #pragma unroll
    for (int r = 0; r < 16; ++r) y[r] = make_float2(0.f, 0.f);
    #pragma unroll 2
    for (int k = 0; k < 64; ++k) {
        float2 x = Bm[c * 65 + k];                  // own column, 2-way bank (free)
        #pragma unroll
        for (int r = 0; r < 16; ++r) {
            float2 a = A[k * 65 + 16 * rq + r];     // wave-uniform -> broadcast
            y[r].x = fmaf(a.x, x.x, fmaf(-a.y, x.y, y[r].x));
            y[r].y = fmaf(a.x, x.y, fmaf( a.y, x.x, y[r].y));
        }
    }
}

__device__ __forceinline__ void store_split(unsigned short* AH, unsigned short* AL,
                                            int l, int m, int k, float v)
{
    int o = afrag_off(l, m, k);
    unsigned short h = f2bf(v);
    AH[o] = h;
    AL[o] = f2bf(v - bf2f(h));
}

// ---------------------------------------------------------------------------
// Kernel 1: build_all. 73 blocks x 256 threads.
//  blocks 0..4  : layer l. Phase1: coop sincos -> cs scratch (LDS, overlaps the
//                 B-buffer region, consumed before P writes) + ocs. Phase2: wave
//                 s scans segment s in registers (64 cols/wave). Phase3: write P
//                 into padded B-buffers. Phase4: T1=P1*P0, T2=P3*P2, U=T2*T1,
//                 fold psi, store split-bf16 A-frags.
//  blocks 5..72 : weight prep (W1->slot5, W2->slot6, W3T, nofu consts).
// ---------------------------------------------------------------------------
__global__ __launch_bounds__(256, 1) void build_all(
    const float* __restrict__ mzi, const float* __restrict__ oph,
    const float* __restrict__ W1,  const float* __restrict__ W2,
    const float* __restrict__ W3,  const float* __restrict__ beta_param,
    const float* __restrict__ det0, unsigned short* __restrict__ AH)
{
    unsigned short* AL = AH + AH_SHORTS;
    extern __shared__ float cl[];
    const int tid = threadIdx.x;

    if (blockIdx.x >= LL) {
        // ---------------- weight-prep role ----------------
        float* fbase = (float*)((char*)AH + FLOAT_BYTE);
        float* nofuF = fbase;               // 1024 floats (256 x float4)
        float* W3T   = fbase + 1024;        // 768 floats
        int idx = (blockIdx.x - LL) * 256 + tid;
        if (idx < 8192) {                        // W1 (128x64)
            int mm = idx >> 6, k = idx & 63;
            float v = W1[idx];
            unsigned short h = f2bf(v);
            int o = afrag_off(5, mm, k);
            AH[o] = h; AL[o] = f2bf(v - bf2f(h));
        } else if (idx < 16384) {                // W2 (64x128)
            int t = idx - 8192;
            int mm = t >> 7, k = t & 127;
            float v = W2[t];
            unsigned short h = f2bf(v);
            int o = afrag_off(6, mm, k);
            AH[o] = h; AL[o] = f2bf(v - bf2f(h));
        } else if (idx < 17152) {                // W3 (12x64) -> W3T[j][r]
            int t = idx - 16384;
            int r = t >> 6, j = t & 63;
            W3T[j * 12 + r] = W3[t];
        } else if (idx < 17408) {                // nofu consts, t = l*64+row
            int t = idx - 17152;
            float bp = beta_param[t];
            float beta = 1.f / (1.f + expf(-bp));
            float* p = nofuF + t * 4;
            p[0] = SENSRESP * beta;
            p[1] = sqrtf(fmaxf(1.f - beta, 0.f)) * GAMMA_;
            p[2] = det0[t];
            p[3] = 0.f;
        }
        return;
    }

    // ---------------- unitary-build role ----------------
    float2* B0 = (float2*)cl;              // 64 x 65 f2 each
    float2* B1 = B0 + 4160;
    float2* B2 = B1 + 4160;
    float2* B3 = B2 + 4160;
    float2* ocs = B3 + 4160;               // 64 f2  (floats 33280..33407)
    float* csb = cl;                       // cs scratch [4][531][4] = 8496 floats,
                                           // overlaps B-region; dead before P writes
    const int l = blockIdx.x;
    const int M0s[5] = {0, 531, 1026, 1488, 2016};

    // Phase 1: cs + ocs tables
    for (int m = tid; m < NMZI; m += 256) {
        int s = (m >= 531) + (m >= 1026) + (m >= 1488);
        int t = m - M0s[s];
        float th = mzi[l * 2 * NMZI + 2 * m];
        float ph = mzi[l * 2 * NMZI + 2 * m + 1];
        float sth, cth, sph, cph;
        sincosf(th, &sth, &cth);
        sincosf(ph, &sph, &cph);
        float* p = csb + ((s * 531 + t) << 2);
        p[0] = cph; p[1] = sph;
        p[2] = C_HALF * cth; p[3] = C_HALF * sth;
    }
    if (tid < NN) {
        float sp, cp; sincosf(oph[l * NN + tid], &sp, &cp);
        ocs[tid] = make_float2(cp, sp);
    }
    __syncthreads();

    // Phase 2: wave s scans segment s; thread = column c; state in registers
    const int wv = tid >> 6;               // wave-uniform
    const int c  = tid & 63;
    float ur[NN], ui[NN];
    #pragma unroll
    for (int r = 0; r < NN; ++r) { ur[r] = (r == c) ? 1.f : 0.f; ui[r] = 0.f; }
    {
        const float (*cs)[4] = (const float (*)[4])(csb + ((wv * 531) << 2));
        switch (wv) {
            case 0: run_scan<0,  9>(cs, ur, ui); break;
            case 1: run_scan<9, 19>(cs, ur, ui); break;
            case 2: run_scan<19,31>(cs, ur, ui); break;
            default:run_scan<31,63>(cs, ur, ui); break;
        }
    }
    __syncthreads();                       // all cs reads done before overwrite

    // Phase 3: P_s -> padded buffer: Bs[c*65 + r] = P_s(r, c)
    {
        float2* Bs = B0 + wv * 4160;
        #pragma unroll
        for (int r = 0; r < NN; ++r) Bs[c * 65 + r] = make_float2(ur[r], ui[r]);
    }
    __syncthreads();

    // Phase 4: combine. thread = (row-quarter rq, col c)
    const int rq = wv;
    float2 t1[16], t2[16];
    cpass(B1, B0, rq, c, t1);   // T1 = P1*P0
    cpass(B3, B2, rq, c, t2);   // T2 = P3*P2
    __syncthreads();
    #pragma unroll
    for (int r = 0; r < 16; ++r) {
        B0[c * 65 + 16 * rq + r] = t1[r];
        B2[c * 65 + 16 * rq + r] = t2[r];
    }
    __syncthreads();

    float2 u[16];
    cpass(B2, B0, rq, c, u);    // U = T2*T1

    #pragma unroll
    for (int r = 0; r < 16; ++r) {
        int mr = 16 * rq + r;
        float2 oc = ocs[mr];
        float vr = oc.x * u[r].x - oc.y * u[r].y;   // e^{i psi_mr} * U[mr][c]
        float vi = oc.x * u[r].y + oc.y * u[r].x;
        // Mat = [[Ur,-Ui],[Ui,Ur]]
        store_split(AH, AL, l, mr,      c,      vr);
        store_split(AH, AL, l, mr,      c + 64, -vi);
        store_split(AH, AL, l, mr + 64, c,      vi);
        store_split(AH, AL, l, mr + 64, c + 64, vr);
    }
}

// ---------------------------------------------------------------------------
// mm_block (R8 verbatim): C[Mt tile(s)] += A_slot x F. PAIR: also Mt0+4 -> acc1.
// F planes XOR-swizzled: physical byte = row*256 + (cbyte ^ ((row&7)<<4)).
// ---------------------------------------------------------------------------
template<int K4, bool PAIR>
__device__ __forceinline__ void mm_block(
    const unsigned short* __restrict__ AH, const unsigned short* __restrict__ AL,
    const unsigned short* Fh, const unsigned short* Fl,
    int slot, int mt0, int lane, int q, int x0, const int* rowb,
    f32x4* acc0, f32x4* acc1)
{
    #pragma unroll
    for (int Kt = 0; Kt < K4; ++Kt) {
        int off0 = (((slot * 8 + mt0) * 4 + Kt) << 9);
        U4S8 ah0, al0, ah1, al1;
        ah0.u = ((const uint4*)(AH + off0))[lane];
        al0.u = ((const uint4*)(AL + off0))[lane];
        if (PAIR) {
            ah1.u = ((const uint4*)(AH + off0 + 8192))[lane];   // Mt0+4
            al1.u = ((const uint4*)(AL + off0 + 8192))[lane];
        }
        const int cb = (64 * Kt + 16 * q) ^ x0;
        #pragma unroll
        for (int t = 0; t < 4; ++t) {
            short8 bh = *(const short8*)((const char*)Fh + rowb[t] + cb);
            short8 bl = *(const short8*)((const char*)Fl + rowb[t] + cb);
            acc0[t] = MFMA16(ah0.s, bh, acc0[t]);
            acc0[t] = MFMA16(ah0.s, bl, acc0[t]);
            acc0[t] = MFMA16(al0.s, bh, acc0[t]);
            if (PAIR) {
                acc1[t] = MFMA16(ah1.s, bh, acc1[t]);
                acc1[t] = MFMA16(ah1.s, bl, acc1[t]);
                acc1[t] = MFMA16(al1.s, bh, acc1[t]);
            }
        }
    }
}

// ---------------------------------------------------------------------------
// Kernel 2: main (R8 verbatim). 64 samples/block, 256 threads (4 waves).
// F: 2 planes x 64 rows x 256 B, XOR-swizzled, 32768 B total.
// ---------------------------------------------------------------------------
__global__ __launch_bounds__(256, 5) void ficonn_main(
    const float* __restrict__ x,
    const float* __restrict__ b1,
    const float* __restrict__ b2,
    const float* __restrict__ b3,
    const unsigned short* __restrict__ AH,
    const float4* __restrict__ nofuC,
    const float* __restrict__ W3T,
    float* __restrict__ out)
{
    const unsigned short* AL = AH + AH_SHORTS;
    extern __shared__ unsigned short Fdyn[];
    unsigned short* Fh = Fdyn;                  // 64 rows x 256 B, swizzled
    unsigned short* Fl = Fdyn + 8192;           // same

    const int tid  = threadIdx.x;
    const int lane = tid & 63;
    const int w    = __builtin_amdgcn_readfirstlane(tid >> 6);   // 0..3
    const int mp   = w;
    const int n16  = lane & 15, q = lane >> 4;
    const int base = blockIdx.x * 64;

    // ---- stage x (split bf16, hi/lo planes); input real -> cbyte < 128 only ----
    {
        const float4* x4 = (const float4*)(x + (size_t)base * 64);
        #pragma unroll
        for (int it = 0; it < 4; ++it) {
            int idx = tid + it * 256;           // 1024 float4
            int j4 = idx & 15, ss = idx >> 4;
            float4 v4 = x4[idx];
            float vv[4] = {v4.x, v4.y, v4.z, v4.w};
            uint2 hi, lo; split4(vv, hi, lo);
            int off = (ss << 8) + ((8 * j4) ^ ((ss & 7) << 4));
            *(uint2*)((char*)Fh + off) = hi;
            *(uint2*)((char*)Fl + off) = lo;
        }
    }
    __syncthreads();

    const int x0 = (n16 & 7) << 4;              // per-lane col XOR (row&7 == n16&7)
    int rowb[4];
    #pragma unroll
    for (int t = 0; t < 4; ++t) rowb[t] = (16 * t + n16) << 8;
    const int kw  = 16 * mp + 4 * q;            // logical output k-base (shorts)
    const int cwr = (32 * mp + 8 * q) ^ x0;     // swizzled byte col for writes

    // ================= 5 unitary layers =================
    #pragma unroll 1
    for (int l = 0; l < 5; ++l) {
        f32x4 acc0[4], acc1[4];
        #pragma unroll
        for (int t = 0; t < 4; ++t)
            #pragma unroll
            for (int r = 0; r < 4; ++r) { acc0[t][r] = 0.f; acc1[t][r] = 0.f; }

        if (l == 0) mm_block<2, true>(AH, AL, Fh, Fl, 0, mp, lane, q, x0, rowb, acc0, acc1);
        else        mm_block<4, true>(AH, AL, Fh, Fl, l, mp, lane, q, x0, rowb, acc0, acc1);
        __syncthreads();   // all F reads done

        if (l < 4) {
            float4 nc[4];
            #pragma unroll
            for (int r = 0; r < 4; ++r) nc[r] = nofuC[l * 64 + kw + r];
            #pragma unroll
            for (int t = 0; t < 4; ++t) {
                float wr[4], wi[4];
                #pragma unroll
                for (int r = 0; r < 4; ++r) {
                    float yr = acc0[t][r], yi = acc1[t][r];
                    float4 c = nc[r];
                    float p   = fmaf(yr, yr, yi * yi);
                    float det = fmaf(c.x, p, c.z);
                    float sc  = c.y * __builtin_amdgcn_rcpf(fmaf(det, det, GAMMA_ * GAMMA_));
                    float tr = sc * GAMMA_, ti = sc * det;
                    wr[r] = fmaf(tr, yr,  ti * yi);
                    wi[r] = fmaf(tr, yi, -ti * yr);
                }
                uint2 hi, lo;
                split4(wr, hi, lo);
                *(uint2*)((char*)Fh + rowb[t] + cwr) = hi;
                *(uint2*)((char*)Fl + rowb[t] + cwr) = lo;
                split4(wi, hi, lo);
                *(uint2*)((char*)Fh + rowb[t] + cwr + 128) = hi;
                *(uint2*)((char*)Fl + rowb[t] + cwr + 128) = lo;
            }
        } else {
            #pragma unroll
            for (int t = 0; t < 4; ++t) {
                float pw[4];
                #pragma unroll
                for (int r = 0; r < 4; ++r)
                    pw[r] = fmaf(acc0[t][r], acc0[t][r], acc1[t][r] * acc1[t][r]);
                uint2 hi, lo;
                split4(pw, hi, lo);
                *(uint2*)((char*)Fh + rowb[t] + cwr) = hi;
                *(uint2*)((char*)Fl + rowb[t] + cwr) = lo;
            }
        }
        __syncthreads();
    }

    // ================= W1: M=128, K=64 (slot 5), Mt in {mp, mp+4} =================
    {
        f32x4 acc0[4], acc1[4];
        #pragma unroll
        for (int t = 0; t < 4; ++t)
            #pragma unroll
            for (int r = 0; r < 4; ++r) { acc0[t][r] = 0.f; acc1[t][r] = 0.f; }

        mm_block<2, true>(AH, AL, Fh, Fl, 5, mp, lane, q, x0, rowb, acc0, acc1);
        __syncthreads();

        float4 bb0 = *(const float4*)&b1[kw];
        float4 bb1 = *(const float4*)&b1[kw + 64];
        #pragma unroll
        for (int t = 0; t < 4; ++t) {
            float h0[4], h1v[4];
            #pragma unroll
            for (int r = 0; r < 4; ++r) {
                h0[r]  = fmaxf(acc0[t][r] + ((const float*)&bb0)[r], 0.f);
                h1v[r] = fmaxf(acc1[t][r] + ((const float*)&bb1)[r], 0.f);
            }
            uint2 hi, lo;
            split4(h0, hi, lo);
            *(uint2*)((char*)Fh + rowb[t] + cwr) = hi;
            *(uint2*)((char*)Fl + rowb[t] + cwr) = lo;
            split4(h1v, hi, lo);
            *(uint2*)((char*)Fh + rowb[t] + cwr + 128) = hi;
            *(uint2*)((char*)Fl + rowb[t] + cwr + 128) = lo;
        }
        __syncthreads();
    }

    // ================= W2: M=64, K=128 (slot 6), Mt=mp =================
    {
        f32x4 acc0[4], acc1[4];   // acc1 unused
        #pragma unroll
        for (int t = 0; t < 4; ++t)
            #pragma unroll
            for (int r = 0; r < 4; ++r) acc0[t][r] = 0.f;

        mm_block<4, false>(AH, AL, Fh, Fl, 6, mp, lane, q, x0, rowb, acc0, acc1);
        __syncthreads();

        float4 bb = *(const float4*)&b2[kw];
        #pragma unroll
        for (int t = 0; t < 4; ++t) {
            float h[4];
            #pragma unroll
            for (int r = 0; r < 4; ++r)
                h[r] = fmaxf(acc0[t][r] + ((const float*)&bb)[r], 0.f);
            uint2 hi, lo;
            split4(h, hi, lo);
            *(uint2*)((char*)Fh + rowb[t] + cwr) = hi;
            *(uint2*)((char*)Fl + rowb[t] + cwr) = lo;
        }
        __syncthreads();
    }

    // ================= W3: fp32 VALU, all 256 threads: (sample, out-triple) ===
    {
        const int n  = tid & 63;
        const int rg = __builtin_amdgcn_readfirstlane(tid >> 6);   // 0..3 (uniform)
        float o0 = b3[3 * rg], o1 = b3[3 * rg + 1], o2 = b3[3 * rg + 2];
        const char* rh = (const char*)Fh + (n << 8);
        const char* rl = (const char*)Fl + (n << 8);
        const int xr = (n & 7) << 4;
        #pragma unroll
        for (int kc = 0; kc < 8; ++kc) {
            int cb = (16 * kc) ^ xr;
            uint4 ph = *(const uint4*)(rh + cb);
            uint4 pl = *(const uint4*)(rl + cb);
            unsigned hu[4] = {ph.x, ph.y, ph.z, ph.w};
            unsigned lu[4] = {pl.x, pl.y, pl.z, pl.w};
            #pragma unroll
            for (int e = 0; e < 4; ++e) {
                int k = 8 * kc + 2 * e;
                float ha = __uint_as_float(hu[e] << 16)
                         + __uint_as_float(lu[e] << 16);
                float hb = __uint_as_float(hu[e] & 0xffff0000u)
                         + __uint_as_float(lu[e] & 0xffff0000u);
                const float* wa = W3T + k * 12 + 3 * rg;
                const float* wb = wa + 12;
                o0 = fmaf(wa[0], ha, fmaf(wb[0], hb, o0));
                o1 = fmaf(wa[1], ha, fmaf(wb[1], hb, o1));
                o2 = fmaf(wa[2], ha, fmaf(wb[2], hb, o2));
            }
        }
        float* op = out + (size_t)(base + n) * 12 + 3 * rg;
        op[0] = o0; op[1] = o1; op[2] = o2;
    }
}

extern "C" void kernel_launch(void* const* d_in, const int* in_sizes, int n_in,
                              void* d_out, int out_size, void* d_ws, size_t ws_size,
                              hipStream_t stream)
{
    const float* x    = (const float*)d_in[0];
    const float* mzi  = (const float*)d_in[1];
    const float* oph  = (const float*)d_in[2];
    const float* beta = (const float*)d_in[3];
    const float* det0 = (const float*)d_in[4];
    const float* W1   = (const float*)d_in[5];
    const float* b1   = (const float*)d_in[6];
    const float* W2   = (const float*)d_in[7];
    const float* b2   = (const float*)d_in[8];
    const float* W3   = (const float*)d_in[9];
    const float* b3   = (const float*)d_in[10];
    float* out = (float*)d_out;

    unsigned short* AH = (unsigned short*)d_ws;
    float* fbase = (float*)((char*)d_ws + FLOAT_BYTE);
    const float4* nofuC = (const float4*)fbase;
    const float* W3T = fbase + 1024;

    const int B = in_sizes[0] / NN;       // 262144
    const int blocks = B / 64;            // 4096
    const size_t main_lds  = 32768;       // 2 planes x 64 x 256 B (swizzled)
    const size_t build_lds = (4u * 4160u + 64u) * sizeof(float2);        // 133632

    hipLaunchKernelGGL(build_all, dim3(LL + 68), dim3(256), build_lds, stream,
                       mzi, oph, W1, W2, W3, beta, det0, AH);
    hipLaunchKernelGGL(ficonn_main, dim3(blocks), dim3(256), main_lds, stream,
                       x, b1, b2, b3, AH, nofuC, W3T, out);
}

// Round 8
// 316.527 us; speedup vs baseline: 1.3763x; 1.0205x over previous
//
#include <hip/hip_runtime.h>
#include <math.h>

// FICONN forward, split-bf16 MFMA (hi+lo, 3-product).
// R14 = R13 + per-block START STAGGER (s_sleep keyed on blockIdx) in ficonn_main.
//   R13 counters: MfmaUtil 44.4 + VALUBusy 57.0 = 101% -> CU always issuing but
//   NEVER co-issuing: wall(151) = VALU(86) + MFMA(67). Cause: all blocks launch
//   in lockstep, identical phase durations keep co-resident blocks phase-locked
//   for the whole dispatch -> every wave on a CU is in the same {mm|epi} phase.
//   Fix: one-time 0/960/1920/2880-cycle sleep, key (blockIdx ^ blockIdx>>8)&3
//   (dephases under consecutive-fill OR stride-256 residency). Phase ~3.5-4k cyc
//   -> co-residents land at distinct phase positions; offset persists across
//   rounds. No arithmetic change. Smoking gun if right: Mfma+VALU sum > 110%.

#define NN 64
#define LL 5
#define NMZI 2016
#define C_HALF 0.7071067811865476f
#define GAMMA_ 0.05f
#define SENSRESP 0.0008f     // SENS*RESP

#define AH_SHORTS   114688   // 7 slots * 8Mt * 4Kt * 512 shorts
#define FLOAT_BYTE  458752   // nofuC (1024 f) + W3T (768 f)

typedef short short8 __attribute__((ext_vector_type(8)));
typedef float f32x4  __attribute__((ext_vector_type(4)));

union U4S8 { uint4 u; short8 s; };

#define MFMA16(a, b, c) __builtin_amdgcn_mfma_f32_16x16x32_bf16((a), (b), (c), 0, 0, 0)

__device__ __forceinline__ unsigned short f2bf(float f) {
    unsigned u = __float_as_uint(f);
    unsigned r = u + 0x7fffu + ((u >> 16) & 1u);
    return (unsigned short)(r >> 16);
}
__device__ __forceinline__ float bf2f(unsigned short h) {
    return __uint_as_float(((unsigned)h) << 16);
}
// packed bf16 convert: bits[15:0]=bf16(a), bits[31:16]=bf16(b)  (RNE)
__device__ __forceinline__ unsigned cvtpk(float a, float b) {
    unsigned r;
    asm("v_cvt_pk_bf16_f32 %0, %1, %2" : "=v"(r) : "v"(a), "v"(b));
    return r;
}
// split 4 floats into packed-bf16 hi plane + packed-bf16 residual plane.
__device__ __forceinline__ void split4(const float* v, uint2& hi, uint2& lo) {
    hi.x = cvtpk(v[0], v[1]);
    hi.y = cvtpk(v[2], v[3]);
    float l0 = v[0] - __uint_as_float(hi.x << 16);
    float l1 = v[1] - __uint_as_float(hi.x & 0xffff0000u);
    float l2 = v[2] - __uint_as_float(hi.y << 16);
    float l3 = v[3] - __uint_as_float(hi.y & 0xffff0000u);
    lo.x = cvtpk(l0, l1);
    lo.y = cvtpk(l2, l3);
}
// frag-linear offset (in shorts) of element (m,k) of A-slot l (16x16x32 layout)
__device__ __forceinline__ int afrag_off(int l, int m, int k) {
    return ((((l * 8 + (m >> 4)) * 4 + (k >> 5)) << 9)
          + ((((k >> 3) & 3) * 16 + (m & 15)) << 3) + (k & 7));
}

// ---------------------------------------------------------------------------
// scan: exact R4-proven register scan over one segment's MZI steps.
// ---------------------------------------------------------------------------
template<int I0, int I1>
__device__ __forceinline__ void run_scan(const float cs[][4], float* ur, float* ui)
{
    int m = 0;
    #pragma unroll
    for (int i = I0; i < I1; ++i) {
        #pragma unroll
        for (int j = i + 1; j < NN; ++j) {
            float cph = cs[m][0], sph = cs[m][1];
            float cct = cs[m][2], cst = cs[m][3];
            float tr = cph * ur[j] - sph * ui[j];
            float ti = cph * ui[j] + sph * ur[j];
            float ar = ur[i] + tr, ai = ui[i] + ti;
            float sr = ur[i] - tr, si = ui[i] - ti;
            ur[i] = C_HALF * ar;
            ui[i] = C_HALF * ai;
            ur[j] = cct * sr - cst * si;
            ui[j] = cct * si + cst * sr;
            ++m;
        }
    }
}

__device__ __forceinline__ void cpass(const float2* A, const float2* Bm,
                                      int rq, int c, float2* y)
{
    #pragma unroll
    for (int r = 0; r < 16; ++r) y[r] = make_float2(0.f, 0.f);
    #pragma unroll 2
    for (int k = 0; k < 64; ++k) {
        float2 x = Bm[c * 65 + k];                  // own column, 2-way bank (free)
        #pragma unroll
        for (int r = 0; r < 16; ++r) {
            float2 a = A[k * 65 + 16 * rq + r];     // wave-uniform -> broadcast
            y[r].x = fmaf(a.x, x.x, fmaf(-a.y, x.y, y[r].x));
            y[r].y = fmaf(a.x, x.y, fmaf( a.y, x.x, y[r].y));
        }
    }
}

__device__ __forceinline__ void store_split(unsigned short* AH, unsigned short* AL,
                                            int l, int m, int k, float v)
{
    int o = afrag_off(l, m, k);
    unsigned short h = f2bf(v);
    AH[o] = h;
    AL[o] = f2bf(v - bf2f(h));
}

// ---------------------------------------------------------------------------
// Kernel 1: build_all. 73 blocks x 256 threads.
//  blocks 0..4  : layer l. Phase1: coop sincos -> cs scratch (LDS, overlaps the
//                 B-buffer region, consumed before P writes) + ocs. Phase2: wave
//                 s scans segment s in registers (64 cols/wave). Phase3: write P
//                 into padded B-buffers. Phase4: T1=P1*P0, T2=P3*P2, U=T2*T1,
//                 fold psi, store split-bf16 A-frags.
//  blocks 5..72 : weight prep (W1->slot5, W2->slot6, W3T, nofu consts).
// ---------------------------------------------------------------------------
__global__ __launch_bounds__(256, 1) void build_all(
    const float* __restrict__ mzi, const float* __restrict__ oph,
    const float* __restrict__ W1,  const float* __restrict__ W2,
    const float* __restrict__ W3,  const float* __restrict__ beta_param,
    const float* __restrict__ det0, unsigned short* __restrict__ AH)
{
    unsigned short* AL = AH + AH_SHORTS;
    extern __shared__ float cl[];
    const int tid = threadIdx.x;

    if (blockIdx.x >= LL) {
        // ---------------- weight-prep role ----------------
        float* fbase = (float*)((char*)AH + FLOAT_BYTE);
        float* nofuF = fbase;               // 1024 floats (256 x float4)
        float* W3T   = fbase + 1024;        // 768 floats
        int idx = (blockIdx.x - LL) * 256 + tid;
        if (idx < 8192) {                        // W1 (128x64)
            int mm = idx >> 6, k = idx & 63;
            float v = W1[idx];
            unsigned short h = f2bf(v);
            int o = afrag_off(5, mm, k);
            AH[o] = h; AL[o] = f2bf(v - bf2f(h));
        } else if (idx < 16384) {                // W2 (64x128)
            int t = idx - 8192;
            int mm = t >> 7, k = t & 127;
            float v = W2[t];
            unsigned short h = f2bf(v);
            int o = afrag_off(6, mm, k);
            AH[o] = h; AL[o] = f2bf(v - bf2f(h));
        } else if (idx < 17152) {                // W3 (12x64) -> W3T[j][r]
            int t = idx - 16384;
            int r = t >> 6, j = t & 63;
            W3T[j * 12 + r] = W3[t];
        } else if (idx < 17408) {                // nofu consts, t = l*64+row
            int t = idx - 17152;
            float bp = beta_param[t];
            float beta = 1.f / (1.f + expf(-bp));
            float* p = nofuF + t * 4;
            p[0] = SENSRESP * beta;
            p[1] = sqrtf(fmaxf(1.f - beta, 0.f)) * GAMMA_;
            p[2] = det0[t];
            p[3] = 0.f;
        }
        return;
    }

    // ---------------- unitary-build role ----------------
    float2* B0 = (float2*)cl;              // 64 x 65 f2 each
    float2* B1 = B0 + 4160;
    float2* B2 = B1 + 4160;
    float2* B3 = B2 + 4160;
    float2* ocs = B3 + 4160;               // 64 f2  (floats 33280..33407)
    float* csb = cl;                       // cs scratch [4][531][4] = 8496 floats,
                                           // overlaps B-region; dead before P writes
    const int l = blockIdx.x;
    const int M0s[5] = {0, 531, 1026, 1488, 2016};

    // Phase 1: cs + ocs tables
    for (int m = tid; m < NMZI; m += 256) {
        int s = (m >= 531) + (m >= 1026) + (m >= 1488);
        int t = m - M0s[s];
        float th = mzi[l * 2 * NMZI + 2 * m];
        float ph = mzi[l * 2 * NMZI + 2 * m + 1];
        float sth, cth, sph, cph;
        sincosf(th, &sth, &cth);
        sincosf(ph, &sph, &cph);
        float* p = csb + ((s * 531 + t) << 2);
        p[0] = cph; p[1] = sph;
        p[2] = C_HALF * cth; p[3] = C_HALF * sth;
    }
    if (tid < NN) {
        float sp, cp; sincosf(oph[l * NN + tid], &sp, &cp);
        ocs[tid] = make_float2(cp, sp);
    }
    __syncthreads();

    // Phase 2: wave s scans segment s; thread = column c; state in registers
    const int wv = tid >> 6;               // wave-uniform
    const int c  = tid & 63;
    float ur[NN], ui[NN];
    #pragma unroll
    for (int r = 0; r < NN; ++r) { ur[r] = (r == c) ? 1.f : 0.f; ui[r] = 0.f; }
    {
        const float (*cs)[4] = (const float (*)[4])(csb + ((wv * 531) << 2));
        switch (wv) {
            case 0: run_scan<0,  9>(cs, ur, ui); break;
            case 1: run_scan<9, 19>(cs, ur, ui); break;
            case 2: run_scan<19,31>(cs, ur, ui); break;
            default:run_scan<31,63>(cs, ur, ui); break;
        }
    }
    __syncthreads();                       // all cs reads done before overwrite

    // Phase 3: P_s -> padded buffer: Bs[c*65 + r] = P_s(r, c)
    {
        float2* Bs = B0 + wv * 4160;
        #pragma unroll
        for (int r = 0; r < NN; ++r) Bs[c * 65 + r] = make_float2(ur[r], ui[r]);
    }
    __syncthreads();

    // Phase 4: combine. thread = (row-quarter rq, col c)
    const int rq = wv;
    float2 t1[16], t2[16];
    cpass(B1, B0, rq, c, t1);   // T1 = P1*P0
    cpass(B3, B2, rq, c, t2);   // T2 = P3*P2
    __syncthreads();
    #pragma unroll
    for (int r = 0; r < 16; ++r) {
        B0[c * 65 + 16 * rq + r] = t1[r];
        B2[c * 65 + 16 * rq + r] = t2[r];
    }
    __syncthreads();

    float2 u[16];
    cpass(B2, B0, rq, c, u);    // U = T2*T1

    #pragma unroll
    for (int r = 0; r < 16; ++r) {
        int mr = 16 * rq + r;
        float2 oc = ocs[mr];
        float vr = oc.x * u[r].x - oc.y * u[r].y;   // e^{i psi_mr} * U[mr][c]
        float vi = oc.x * u[r].y + oc.y * u[r].x;
        // Mat = [[Ur,-Ui],[Ui,Ur]]
        store_split(AH, AL, l, mr,      c,      vr);
        store_split(AH, AL, l, mr,      c + 64, -vi);
        store_split(AH, AL, l, mr + 64, c,      vi);
        store_split(AH, AL, l, mr + 64, c + 64, vr);
    }
}

// ---------------------------------------------------------------------------
// mm_block (R8 verbatim): C[Mt tile(s)] += A_slot x F. PAIR: also Mt0+4 -> acc1.
// F planes XOR-swizzled: physical byte = row*256 + (cbyte ^ ((row&7)<<4)).
// ---------------------------------------------------------------------------
template<int K4, bool PAIR>
__device__ __forceinline__ void mm_block(
    const unsigned short* __restrict__ AH, const unsigned short* __restrict__ AL,
    const unsigned short* Fh, const unsigned short* Fl,
    int slot, int mt0, int lane, int q, int x0, const int* rowb,
    f32x4* acc0, f32x4* acc1)
{
    #pragma unroll
    for (int Kt = 0; Kt < K4; ++Kt) {
        int off0 = (((slot * 8 + mt0) * 4 + Kt) << 9);
        U4S8 ah0, al0, ah1, al1;
        ah0.u = ((const uint4*)(AH + off0))[lane];
        al0.u = ((const uint4*)(AL + off0))[lane];
        if (PAIR) {
            ah1.u = ((const uint4*)(AH + off0 + 8192))[lane];   // Mt0+4
            al1.u = ((const uint4*)(AL + off0 + 8192))[lane];
        }
        const int cb = (64 * Kt + 16 * q) ^ x0;
        #pragma unroll
        for (int t = 0; t < 4; ++t) {
            short8 bh = *(const short8*)((const char*)Fh + rowb[t] + cb);
            short8 bl = *(const short8*)((const char*)Fl + rowb[t] + cb);
            acc0[t] = MFMA16(ah0.s, bh, acc0[t]);
            acc0[t] = MFMA16(ah0.s, bl, acc0[t]);
            acc0[t] = MFMA16(al0.s, bh, acc0[t]);
            if (PAIR) {
                acc1[t] = MFMA16(ah1.s, bh, acc1[t]);
                acc1[t] = MFMA16(ah1.s, bl, acc1[t]);
                acc1[t] = MFMA16(al1.s, bh, acc1[t]);
            }
        }
    }
}

// ---------------------------------------------------------------------------
// Kernel 2: main (R8 structure + start stagger). 64 samples/block, 256 threads.
// F: 2 planes x 64 rows x 256 B, XOR-swizzled, 32768 B total.
// ---------------------------------------------------------------------------
__global__ __launch_bounds__(256, 5) void ficonn_main(
    const float* __restrict__ x,
    const float* __restrict__ b1,
    const float* __restrict__ b2,
    const float* __restrict__ b3,
    const unsigned short* __restrict__ AH,
    const float4* __restrict__ nofuC,
    const float* __restrict__ W3T,
    float* __restrict__ out)
{
    // ---- start stagger: dephase co-resident blocks so mm(MFMA) and epi(VALU)
    // phases of different blocks overlap on the CU. Key covers both plausible
    // residency patterns (consecutive-fill and stride-256 round-robin).
    {
        const int key = (blockIdx.x ^ (blockIdx.x >> 8)) & 3;
        if (key == 1)      __builtin_amdgcn_s_sleep(15);   //  ~960 cyc
        else if (key == 2) __builtin_amdgcn_s_sleep(30);   // ~1920 cyc
        else if (key == 3) __builtin_amdgcn_s_sleep(45);   // ~2880 cyc
    }

    const unsigned short* AL = AH + AH_SHORTS;
    extern __shared__ unsigned short Fdyn[];
    unsigned short* Fh = Fdyn;                  // 64 rows x 256 B, swizzled
    unsigned short* Fl = Fdyn + 8192;           // same

    const int tid  = threadIdx.x;
    const int lane = tid & 63;
    const int w    = __builtin_amdgcn_readfirstlane(tid >> 6);   // 0..3
    const int mp   = w;
    const int n16  = lane & 15, q = lane >> 4;
    const int base = blockIdx.x * 64;

    // ---- stage x (split bf16, hi/lo planes); input real -> cbyte < 128 only ----
    {
        const float4* x4 = (const float4*)(x + (size_t)base * 64);
        #pragma unroll
        for (int it = 0; it < 4; ++it) {
            int idx = tid + it * 256;           // 1024 float4
            int j4 = idx & 15, ss = idx >> 4;
            float4 v4 = x4[idx];
            float vv[4] = {v4.x, v4.y, v4.z, v4.w};
            uint2 hi, lo; split4(vv, hi, lo);
            int off = (ss << 8) + ((8 * j4) ^ ((ss & 7) << 4));
            *(uint2*)((char*)Fh + off) = hi;
            *(uint2*)((char*)Fl + off) = lo;
        }
    }
    __syncthreads();

    const int x0 = (n16 & 7) << 4;              // per-lane col XOR (row&7 == n16&7)
    int rowb[4];
    #pragma unroll
    for (int t = 0; t < 4; ++t) rowb[t] = (16 * t + n16) << 8;
    const int kw  = 16 * mp + 4 * q;            // logical output k-base (shorts)
    const int cwr = (32 * mp + 8 * q) ^ x0;     // swizzled byte col for writes

    // ================= 5 unitary layers =================
    #pragma unroll 1
    for (int l = 0; l < 5; ++l) {
        f32x4 acc0[4], acc1[4];
        #pragma unroll
        for (int t = 0; t < 4; ++t)
            #pragma unroll
            for (int r = 0; r < 4; ++r) { acc0[t][r] = 0.f; acc1[t][r] = 0.f; }

        if (l == 0) mm_block<2, true>(AH, AL, Fh, Fl, 0, mp, lane, q, x0, rowb, acc0, acc1);
        else        mm_block<4, true>(AH, AL, Fh, Fl, l, mp, lane, q, x0, rowb, acc0, acc1);
        __syncthreads();   // all F reads done

        if (l < 4) {
            float4 nc[4];
            #pragma unroll
            for (int r = 0; r < 4; ++r) nc[r] = nofuC[l * 64 + kw + r];
            #pragma unroll
            for (int t = 0; t < 4; ++t) {
                float wr[4], wi[4];
                #pragma unroll
                for (int r = 0; r < 4; ++r) {
                    float yr = acc0[t][r], yi = acc1[t][r];
                    float4 c = nc[r];
                    float p   = fmaf(yr, yr, yi * yi);
                    float det = fmaf(c.x, p, c.z);
                    float sc  = c.y * __builtin_amdgcn_rcpf(fmaf(det, det, GAMMA_ * GAMMA_));
                    float tr = sc * GAMMA_, ti = sc * det;
                    wr[r] = fmaf(tr, yr,  ti * yi);
                    wi[r] = fmaf(tr, yi, -ti * yr);
                }
                uint2 hi, lo;
                split4(wr, hi, lo);
                *(uint2*)((char*)Fh + rowb[t] + cwr) = hi;
                *(uint2*)((char*)Fl + rowb[t] + cwr) = lo;
                split4(wi, hi, lo);
                *(uint2*)((char*)Fh + rowb[t] + cwr + 128) = hi;
                *(uint2*)((char*)Fl + rowb[t] + cwr + 128) = lo;
            }
        } else {
            #pragma unroll
            for (int t = 0; t < 4; ++t) {
                float pw[4];
                #pragma unroll
                for (int r = 0; r < 4; ++r)
                    pw[r] = fmaf(acc0[t][r], acc0[t][r], acc1[t][r] * acc1[t][r]);
                uint2 hi, lo;
                split4(pw, hi, lo);
                *(uint2*)((char*)Fh + rowb[t] + cwr) = hi;
                *(uint2*)((char*)Fl + rowb[t] + cwr) = lo;
            }
        }
        __syncthreads();
    }

    // ================= W1: M=128, K=64 (slot 5), Mt in {mp, mp+4} =================
    {
        f32x4 acc0[4], acc1[4];
        #pragma unroll
        for (int t = 0; t < 4; ++t)
            #pragma unroll
            for (int r = 0; r < 4; ++r) { acc0[t][r] = 0.f; acc1[t][r] = 0.f; }

        mm_block<2, true>(AH, AL, Fh, Fl, 5, mp, lane, q, x0, rowb, acc0, acc1);
        __syncthreads();

        float4 bb0 = *(const float4*)&b1[kw];
        float4 bb1 = *(const float4*)&b1[kw + 64];
        #pragma unroll
        for (int t = 0; t < 4; ++t) {
            float h0[4], h1v[4];
            #pragma unroll
            for (int r = 0; r < 4; ++r) {
                h0[r]  = fmaxf(acc0[t][r] + ((const float*)&bb0)[r], 0.f);
                h1v[r] = fmaxf(acc1[t][r] + ((const float*)&bb1)[r], 0.f);
            }
            uint2 hi, lo;
            split4(h0, hi, lo);
            *(uint2*)((char*)Fh + rowb[t] + cwr) = hi;
            *(uint2*)((char*)Fl + rowb[t] + cwr) = lo;
            split4(h1v, hi, lo);
            *(uint2*)((char*)Fh + rowb[t] + cwr + 128) = hi;
            *(uint2*)((char*)Fl + rowb[t] + cwr + 128) = lo;
        }
        __syncthreads();
    }

    // ================= W2: M=64, K=128 (slot 6), Mt=mp =================
    {
        f32x4 acc0[4], acc1[4];   // acc1 unused
        #pragma unroll
        for (int t = 0; t < 4; ++t)
            #pragma unroll
            for (int r = 0; r < 4; ++r) acc0[t][r] = 0.f;

        mm_block<4, false>(AH, AL, Fh, Fl, 6, mp, lane, q, x0, rowb, acc0, acc1);
        __syncthreads();

        float4 bb = *(const float4*)&b2[kw];
        #pragma unroll
        for (int t = 0; t < 4; ++t) {
            float h[4];
            #pragma unroll
            for (int r = 0; r < 4; ++r)
                h[r] = fmaxf(acc0[t][r] + ((const float*)&bb)[r], 0.f);
            uint2 hi, lo;
            split4(h, hi, lo);
            *(uint2*)((char*)Fh + rowb[t] + cwr) = hi;
            *(uint2*)((char*)Fl + rowb[t] + cwr) = lo;
        }
        __syncthreads();
    }

    // ================= W3: fp32 VALU, all 256 threads: (sample, out-triple) ===
    {
        const int n  = tid & 63;
        const int rg = __builtin_amdgcn_readfirstlane(tid >> 6);   // 0..3 (uniform)
        float o0 = b3[3 * rg], o1 = b3[3 * rg + 1], o2 = b3[3 * rg + 2];
        const char* rh = (const char*)Fh + (n << 8);
        const char* rl = (const char*)Fl + (n << 8);
        const int xr = (n & 7) << 4;
        #pragma unroll
        for (int kc = 0; kc < 8; ++kc) {
            int cb = (16 * kc) ^ xr;
            uint4 ph = *(const uint4*)(rh + cb);
            uint4 pl = *(const uint4*)(rl + cb);
            unsigned hu[4] = {ph.x, ph.y, ph.z, ph.w};
            unsigned lu[4] = {pl.x, pl.y, pl.z, pl.w};
            #pragma unroll
            for (int e = 0; e < 4; ++e) {
                int k = 8 * kc + 2 * e;
                float ha = __uint_as_float(hu[e] << 16)
                         + __uint_as_float(lu[e] << 16);
                float hb = __uint_as_float(hu[e] & 0xffff0000u)
                         + __uint_as_float(lu[e] & 0xffff0000u);
                const float* wa = W3T + k * 12 + 3 * rg;
                const float* wb = wa + 12;
                o0 = fmaf(wa[0], ha, fmaf(wb[0], hb, o0));
                o1 = fmaf(wa[1], ha, fmaf(wb[1], hb, o1));
                o2 = fmaf(wa[2], ha, fmaf(wb[2], hb, o2));
            }
        }
        float* op = out + (size_t)(base + n) * 12 + 3 * rg;
        op[0] = o0; op[1] = o1; op[2] = o2;
    }
}

extern "C" void kernel_launch(void* const* d_in, const int* in_sizes, int n_in,
                              void* d_out, int out_size, void* d_ws, size_t ws_size,
                              hipStream_t stream)
{
    const float* x    = (const float*)d_in[0];
    const float* mzi  = (const float*)d_in[1];
    const float* oph  = (const float*)d_in[2];
    const float* beta = (const float*)d_in[3];
    const float* det0 = (const float*)d_in[4];
    const float* W1   = (const float*)d_in[5];
    const float* b1   = (const float*)d_in[6];
    const float* W2   = (const float*)d_in[7];
    const float* b2   = (const float*)d_in[8];
    const float* W3   = (const float*)d_in[9];
    const float* b3   = (const float*)d_in[10];
    float* out = (float*)d_out;

    unsigned short* AH = (unsigned short*)d_ws;
    float* fbase = (float*)((char*)d_ws + FLOAT_BYTE);
    const float4* nofuC = (const float4*)fbase;
    const float* W3T = fbase + 1024;

    const int B = in_sizes[0] / NN;       // 262144
    const int blocks = B / 64;            // 4096
    const size_t main_lds  = 32768;       // 2 planes x 64 x 256 B (swizzled)
    const size_t build_lds = (4u * 4160u + 64u) * sizeof(float2);        // 133632

    hipLaunchKernelGGL(build_all, dim3(LL + 68), dim3(256), build_lds, stream,
                       mzi, oph, W1, W2, W3, beta, det0, AH);
    hipLaunchKernelGGL(ficonn_main, dim3(blocks), dim3(256), main_lds, stream,
                       x, b1, b2, b3, AH, nofuC, W3T, out);
}